// Round 1
// baseline (1316.276 us; speedup 1.0000x reference)
//
#include <hip/hip_runtime.h>

// ============================================================================
// ProteinLigandGNN: 2x GCNConv (protein), 2x GCNConv (ligand), mean-pool,
// FC + 3 heads.  All f32.
//
// GCNConv: out = D^-1/2 (A+I) D^-1/2 (X W) + b  ==  (D^-1/2 (A+I) D^-1/2 X) W + b
// We aggregate FIRST (in the narrower feature space when possible), then
// transform.  Edge aggregation uses a CSR-by-dst built on device each call:
//   1) count in-degrees (atomics)   2) exclusive scan (1 block)
//   3) scatter src indices by dst (atomic cursor)
// ============================================================================

// ---------------- degree / dinv ----------------
__global__ void count_deg_kernel(const int* __restrict__ dst, int* __restrict__ deg, int E) {
  int e = blockIdx.x * blockDim.x + threadIdx.x;
  if (e < E) atomicAdd(&deg[dst[e]], 1);
}

__global__ void dinv_kernel(const int* __restrict__ deg, float* __restrict__ dinv, int n) {
  int i = blockIdx.x * blockDim.x + threadIdx.x;
  if (i < n) dinv[i] = rsqrtf((float)(deg[i] + 1));  // +1 self-loop; always > 0
}

// ---------------- single-block exclusive scan (n up to ~100k) ----------------
__global__ __launch_bounds__(1024) void exscan_kernel(const int* __restrict__ cnt,
                                                      int* __restrict__ offs, int n) {
  int t = threadIdx.x;
  int lane = t & 63, wid = t >> 6;
  int chunk = (n + 1023) >> 10;
  int beg = t * chunk, end = beg + chunk;
  if (beg > n) beg = n;
  if (end > n) end = n;
  int lsum = 0;
  for (int i = beg; i < end; ++i) lsum += cnt[i];
  // wave inclusive scan
  int v = lsum;
  #pragma unroll
  for (int d = 1; d < 64; d <<= 1) {
    int u = __shfl_up(v, d, 64);
    if (lane >= d) v += u;
  }
  __shared__ int wtot[16];
  if (lane == 63) wtot[wid] = v;
  __syncthreads();
  if (t < 16) {
    int w = wtot[t];
    #pragma unroll
    for (int d = 1; d < 16; d <<= 1) {
      int u = __shfl_up(w, d, 64);
      if (t >= d) w += u;
    }
    wtot[t] = w;
  }
  __syncthreads();
  int excl = (wid ? wtot[wid - 1] : 0) + v - lsum;
  int off = excl;
  for (int i = beg; i < end; ++i) { offs[i] = off; off += cnt[i]; }
  if (t == 1023) offs[n] = off;  // == E
}

// ---------------- scatter edges into CSR ----------------
__global__ void scatter_kernel(const int* __restrict__ src, const int* __restrict__ dst,
                               const int* __restrict__ offs, int* __restrict__ cursor,
                               int* __restrict__ ssrc, int E) {
  int e = blockIdx.x * blockDim.x + threadIdx.x;
  if (e >= E) return;
  int d = dst[e];
  int pos = offs[d] + atomicAdd(&cursor[d], 1);
  ssrc[pos] = src[e];
}

// ---------------- aggregation: out[i] = dinv[i] * (sum_{s->i} x[s]*dinv[s] + x[i]*dinv[i])
// one wave per node.  F <= 64: one float per lane.
template<int F>
__global__ void aggregate_small_kernel(const float* __restrict__ x, const int* __restrict__ ssrc,
                                       const int* __restrict__ offs, const float* __restrict__ dinv,
                                       float* __restrict__ out, int n) {
  int lane = threadIdx.x & 63;
  int node = (blockIdx.x * blockDim.x + threadIdx.x) >> 6;
  if (node >= n) return;
  int beg = offs[node], end = offs[node + 1];
  float acc = 0.f;
  for (int b0 = beg; b0 < end; b0 += 64) {
    int m = end - b0; if (m > 64) m = 64;
    int sl = 0; float wl = 0.f;
    if (lane < m) { sl = ssrc[b0 + lane]; wl = dinv[sl]; }
    for (int k = 0; k < m; ++k) {
      int s = __shfl(sl, k, 64);
      float w = __shfl(wl, k, 64);
      if (lane < F) acc += x[(size_t)s * F + lane] * w;
    }
  }
  if (lane < F) {
    float di = dinv[node];
    acc = (acc + x[(size_t)node * F + lane] * di) * di;
    out[(size_t)node * F + lane] = acc;
  }
}

// F == 128: float2 per lane (512B coalesced row gather per wave)
__global__ void aggregate128_kernel(const float* __restrict__ x, const int* __restrict__ ssrc,
                                    const int* __restrict__ offs, const float* __restrict__ dinv,
                                    float* __restrict__ out, int n) {
  int lane = threadIdx.x & 63;
  int node = (blockIdx.x * blockDim.x + threadIdx.x) >> 6;
  if (node >= n) return;
  int beg = offs[node], end = offs[node + 1];
  float2 acc; acc.x = 0.f; acc.y = 0.f;
  const float2* x2 = (const float2*)x;
  for (int b0 = beg; b0 < end; b0 += 64) {
    int m = end - b0; if (m > 64) m = 64;
    int sl = 0; float wl = 0.f;
    if (lane < m) { sl = ssrc[b0 + lane]; wl = dinv[sl]; }
    for (int k = 0; k < m; ++k) {
      int s = __shfl(sl, k, 64);
      float w = __shfl(wl, k, 64);
      float2 v = x2[(size_t)s * 64 + lane];
      acc.x += v.x * w; acc.y += v.y * w;
    }
  }
  float di = dinv[node];
  float2 vi = x2[(size_t)node * 64 + lane];
  acc.x = (acc.x + vi.x * di) * di;
  acc.y = (acc.y + vi.y * di) * di;
  ((float2*)out)[(size_t)node * 64 + lane] = acc;
}

// ---------------- transform: out[n][128] = relu(in[n][KIN] @ W[KIN][128] + b) ----------------
// 128 threads (one output feature each), NPB nodes per block, W tiled in LDS (K-split 64).
template<int KIN, int NPB>
__global__ __launch_bounds__(128) void transform_relu_kernel(
    const float* __restrict__ in, const float* __restrict__ W,
    const float* __restrict__ bias, float* __restrict__ out, int n) {
  constexpr int KT = (KIN > 64) ? 64 : KIN;
  __shared__ float Ws[KT * 128];
  __shared__ float rowsT[KIN * NPB];  // transposed: [k][j]
  const int f = threadIdx.x;
  const int base = blockIdx.x * NPB;

  // load node rows, transposed into LDS
  for (int i = f; i < NPB * KIN; i += 128) {
    int j = i / KIN, k = i - j * KIN;
    int node = base + j;
    rowsT[k * NPB + j] = (node < n) ? in[(size_t)node * KIN + k] : 0.f;
  }

  float acc[NPB];
  #pragma unroll
  for (int j = 0; j < NPB; ++j) acc[j] = 0.f;

  for (int k0 = 0; k0 < KIN; k0 += KT) {
    __syncthreads();  // protect Ws from previous tile's readers (also fences rowsT writes)
    int kt = KIN - k0; if (kt > KT) kt = KT;
    for (int i = f; i < kt * 128; i += 128) Ws[i] = W[(size_t)k0 * 128 + i];
    __syncthreads();
    for (int k = 0; k < kt; ++k) {
      float w = Ws[k * 128 + f];
      const float4* rt = (const float4*)&rowsT[(k0 + k) * NPB];
      #pragma unroll
      for (int j4 = 0; j4 < NPB / 4; ++j4) {
        float4 r = rt[j4];
        acc[j4 * 4 + 0] += r.x * w;
        acc[j4 * 4 + 1] += r.y * w;
        acc[j4 * 4 + 2] += r.z * w;
        acc[j4 * 4 + 3] += r.w * w;
      }
    }
  }
  float bv = bias[f];
  #pragma unroll
  for (int j = 0; j < NPB; ++j) {
    int node = base + j;
    if (node < n) {
      float v = acc[j] + bv;
      out[(size_t)node * 128 + f] = v > 0.f ? v : 0.f;
    }
  }
}

// ---------------- mean-pool accumulate ----------------
__global__ void pool_kernel(const float* __restrict__ h, const int* __restrict__ batch,
                            float* __restrict__ sum, float* __restrict__ cnt, int n) {
  int i = blockIdx.x * blockDim.x + threadIdx.x;
  int node = i >> 7, f = i & 127;
  if (node >= n) return;
  int g = batch[node];
  atomicAdd(&sum[(size_t)g * 128 + f], h[(size_t)node * 128 + f]);
  if (f == 0) atomicAdd(&cnt[g], 1.0f);
}

// ---------------- final FC + 3 heads ----------------
__global__ __launch_bounds__(128) void fc_heads_kernel(
    const float* __restrict__ pe, const float* __restrict__ le,
    const float* __restrict__ cp, const float* __restrict__ cl,
    const float* __restrict__ Wfc, const float* __restrict__ bfc,
    const float* __restrict__ Wpkd, const float* __restrict__ bpkd,
    const float* __restrict__ Wpki, const float* __restrict__ bpki,
    const float* __restrict__ Wba, const float* __restrict__ bba,
    float* __restrict__ out, int G) {
  int g = blockIdx.x, f = threadIdx.x;
  __shared__ float comb[256];
  __shared__ float cbuf[128];
  float rp = 1.f / fmaxf(cp[g], 1.f);
  float rl = 1.f / fmaxf(cl[g], 1.f);
  comb[f]       = pe[(size_t)g * 128 + f] * rp;
  comb[128 + f] = le[(size_t)g * 128 + f] * rl;
  __syncthreads();
  float acc = bfc[f];
  for (int k = 0; k < 256; ++k) acc += comb[k] * Wfc[(size_t)k * 128 + f];
  cbuf[f] = fmaxf(acc, 0.f);
  __syncthreads();
  if (f < 64) {
    const float* Wh[3] = {Wpkd, Wpki, Wba};
    const float* bh[3] = {bpkd, bpki, bba};
    #pragma unroll
    for (int hd = 0; hd < 3; ++hd) {
      float v = cbuf[f] * Wh[hd][f] + cbuf[f + 64] * Wh[hd][f + 64];
      #pragma unroll
      for (int d = 32; d; d >>= 1) v += __shfl_xor(v, d, 64);
      if (f == 0) out[(size_t)hd * G + g] = v + bh[hd][0];
    }
  }
}

// ============================================================================
static inline size_t alignUp(size_t x, size_t a) { return (x + a - 1) / a * a; }

extern "C" void kernel_launch(void* const* d_in, const int* in_sizes, int n_in,
                              void* d_out, int out_size, void* d_ws, size_t ws_size,
                              hipStream_t stream) {
  const float* px     = (const float*)d_in[0];
  const int*   pei    = (const int*)d_in[1];
  const int*   pbatch = (const int*)d_in[2];
  const float* lx     = (const float*)d_in[3];
  const int*   lei    = (const int*)d_in[4];
  const int*   lbatch = (const int*)d_in[5];
  const float* Wp1 = (const float*)d_in[7],  *bp1 = (const float*)d_in[8];
  const float* Wp2 = (const float*)d_in[9],  *bp2 = (const float*)d_in[10];
  const float* Wl1 = (const float*)d_in[11], *bl1 = (const float*)d_in[12];
  const float* Wl2 = (const float*)d_in[13], *bl2 = (const float*)d_in[14];
  const float* Wfc = (const float*)d_in[15], *bfc = (const float*)d_in[16];
  const float* Wpkd = (const float*)d_in[17], *bpkd = (const float*)d_in[18];
  const float* Wpki = (const float*)d_in[19], *bpki = (const float*)d_in[20];
  const float* Wba  = (const float*)d_in[21], *bba  = (const float*)d_in[22];
  float* out = (float*)d_out;

  const int Np = in_sizes[0] / 23, Ep = in_sizes[1] / 2;
  const int Nl = in_sizes[3] / 4,  El = in_sizes[4] / 2;
  const int G  = out_size / 3;

  // ---- workspace layout (bump allocator, 256B aligned regions) ----
  char* base = (char*)d_ws;
  size_t off = 0;
  auto alloc = [&](size_t bytes) -> void* {
    void* p = base + off;
    off = alignUp(off + bytes, 256);
    return p;
  };
  // zero zone (single memset per call)
  size_t zero_beg = off;
  int*   degcnt_p = (int*)alloc((size_t)Np * 4);
  int*   cursor_p = (int*)alloc((size_t)Np * 4);
  int*   degcnt_l = (int*)alloc((size_t)Nl * 4);
  int*   cursor_l = (int*)alloc((size_t)Nl * 4);
  float* pe_sum   = (float*)alloc((size_t)G * 128 * 4);
  float* le_sum   = (float*)alloc((size_t)G * 128 * 4);
  float* cnt_p    = (float*)alloc((size_t)G * 4);
  float* cnt_l    = (float*)alloc((size_t)G * 4);
  size_t zero_end = off;
  // non-zeroed
  int*   offs_p = (int*)alloc((size_t)(Np + 1) * 4);
  int*   offs_l = (int*)alloc((size_t)(Nl + 1) * 4);
  float* dinv_p = (float*)alloc((size_t)Np * 4);
  float* dinv_l = (float*)alloc((size_t)Nl * 4);
  int*   ssrc_p = (int*)alloc((size_t)Ep * 4);
  int*   ssrc_l = (int*)alloc((size_t)El * 4);
  float* bufA_p = (float*)alloc((size_t)Np * 128 * 4);
  float* bufB_p = (float*)alloc((size_t)Np * 128 * 4);
  float* bufA_l = (float*)alloc((size_t)Nl * 128 * 4);
  float* bufB_l = (float*)alloc((size_t)Nl * 128 * 4);
  if (off > ws_size) return;  // workspace too small -> clean failure

  hipMemsetAsync(base + zero_beg, 0, zero_end - zero_beg, stream);

  const int* psrc = pei;          // row 0
  const int* pdst = pei + Ep;     // row 1
  const int* lsrc = lei;
  const int* ldst = lei + El;

  // ---- CSR build ----
  count_deg_kernel<<<(Ep + 255) / 256, 256, 0, stream>>>(pdst, degcnt_p, Ep);
  count_deg_kernel<<<(El + 255) / 256, 256, 0, stream>>>(ldst, degcnt_l, El);
  dinv_kernel<<<(Np + 255) / 256, 256, 0, stream>>>(degcnt_p, dinv_p, Np);
  dinv_kernel<<<(Nl + 255) / 256, 256, 0, stream>>>(degcnt_l, dinv_l, Nl);
  exscan_kernel<<<1, 1024, 0, stream>>>(degcnt_p, offs_p, Np);
  exscan_kernel<<<1, 1024, 0, stream>>>(degcnt_l, offs_l, Nl);
  scatter_kernel<<<(Ep + 255) / 256, 256, 0, stream>>>(psrc, pdst, offs_p, cursor_p, ssrc_p, Ep);
  scatter_kernel<<<(El + 255) / 256, 256, 0, stream>>>(lsrc, ldst, offs_l, cursor_l, ssrc_l, El);

  // ---- protein GNN ----
  // layer 1: aggregate in input space (23), then transform+relu -> bufA_p (h1)
  aggregate_small_kernel<23><<<(Np + 3) / 4, 256, 0, stream>>>(px, ssrc_p, offs_p, dinv_p, bufB_p, Np);
  transform_relu_kernel<23, 16><<<(Np + 15) / 16, 128, 0, stream>>>(bufB_p, Wp1, bp1, bufA_p, Np);
  // layer 2: aggregate h1 (128), transform+relu -> bufA_p (h2)
  aggregate128_kernel<<<(Np + 3) / 4, 256, 0, stream>>>(bufA_p, ssrc_p, offs_p, dinv_p, bufB_p, Np);
  transform_relu_kernel<128, 16><<<(Np + 15) / 16, 128, 0, stream>>>(bufB_p, Wp2, bp2, bufA_p, Np);

  // ---- ligand GNN ----
  aggregate_small_kernel<4><<<(Nl + 3) / 4, 256, 0, stream>>>(lx, ssrc_l, offs_l, dinv_l, bufB_l, Nl);
  transform_relu_kernel<4, 16><<<(Nl + 15) / 16, 128, 0, stream>>>(bufB_l, Wl1, bl1, bufA_l, Nl);
  aggregate128_kernel<<<(Nl + 3) / 4, 256, 0, stream>>>(bufA_l, ssrc_l, offs_l, dinv_l, bufB_l, Nl);
  transform_relu_kernel<128, 16><<<(Nl + 15) / 16, 128, 0, stream>>>(bufB_l, Wl2, bl2, bufA_l, Nl);

  // ---- mean pool ----
  pool_kernel<<<((size_t)Np * 128 + 255) / 256, 256, 0, stream>>>(bufA_p, pbatch, pe_sum, cnt_p, Np);
  pool_kernel<<<((size_t)Nl * 128 + 255) / 256, 256, 0, stream>>>(bufA_l, lbatch, le_sum, cnt_l, Nl);

  // ---- FC + heads ----
  fc_heads_kernel<<<G, 128, 0, stream>>>(pe_sum, le_sum, cnt_p, cnt_l, Wfc, bfc,
                                         Wpkd, bpkd, Wpki, bpki, Wba, bba, out, G);
}

// Round 2
// 844.747 us; speedup vs baseline: 1.5582x; 1.5582x over previous
//
#include <hip/hip_runtime.h>

// ============================================================================
// ProteinLigandGNN: 2x GCNConv (protein), 2x GCNConv (ligand), mean-pool,
// FC + 3 heads.  All f32.
//
// GCNConv: out = D^-1/2 (A+I) D^-1/2 (X W) + b  ==  (D^-1/2 (A+I) D^-1/2 X) W + b
// Aggregate FIRST (narrow feature space when possible), then transform.
// Edge aggregation uses CSR-by-dst built on device each call.
// Mean-pool: batch arrays are SORTED -> segmented reduction, zero atomics.
// ============================================================================

// ---------------- degree / dinv ----------------
__global__ void count_deg_kernel(const int* __restrict__ dst, int* __restrict__ deg, int E) {
  int e = blockIdx.x * blockDim.x + threadIdx.x;
  if (e < E) atomicAdd(&deg[dst[e]], 1);
}

__global__ void dinv_kernel(const int* __restrict__ deg, float* __restrict__ dinv, int n) {
  int i = blockIdx.x * blockDim.x + threadIdx.x;
  if (i < n) dinv[i] = rsqrtf((float)(deg[i] + 1));  // +1 self-loop; always > 0
}

// ---------------- single-block exclusive scan (n up to ~100k) ----------------
__global__ __launch_bounds__(1024) void exscan_kernel(const int* __restrict__ cnt,
                                                      int* __restrict__ offs, int n) {
  int t = threadIdx.x;
  int lane = t & 63, wid = t >> 6;
  int chunk = (n + 1023) >> 10;
  int beg = t * chunk, end = beg + chunk;
  if (beg > n) beg = n;
  if (end > n) end = n;
  int lsum = 0;
  for (int i = beg; i < end; ++i) lsum += cnt[i];
  int v = lsum;
  #pragma unroll
  for (int d = 1; d < 64; d <<= 1) {
    int u = __shfl_up(v, d, 64);
    if (lane >= d) v += u;
  }
  __shared__ int wtot[16];
  if (lane == 63) wtot[wid] = v;
  __syncthreads();
  if (t < 16) {
    int w = wtot[t];
    #pragma unroll
    for (int d = 1; d < 16; d <<= 1) {
      int u = __shfl_up(w, d, 64);
      if (t >= d) w += u;
    }
    wtot[t] = w;
  }
  __syncthreads();
  int excl = (wid ? wtot[wid - 1] : 0) + v - lsum;
  int off = excl;
  for (int i = beg; i < end; ++i) { offs[i] = off; off += cnt[i]; }
  if (t == 1023) offs[n] = off;  // == E
}

// ---------------- scatter edges into CSR ----------------
__global__ void scatter_kernel(const int* __restrict__ src, const int* __restrict__ dst,
                               const int* __restrict__ offs, int* __restrict__ cursor,
                               int* __restrict__ ssrc, int E) {
  int e = blockIdx.x * blockDim.x + threadIdx.x;
  if (e >= E) return;
  int d = dst[e];
  int pos = offs[d] + atomicAdd(&cursor[d], 1);
  ssrc[pos] = src[e];
}

// ---------------- aggregation ----------------
template<int F>
__global__ void aggregate_small_kernel(const float* __restrict__ x, const int* __restrict__ ssrc,
                                       const int* __restrict__ offs, const float* __restrict__ dinv,
                                       float* __restrict__ out, int n) {
  int lane = threadIdx.x & 63;
  int node = (blockIdx.x * blockDim.x + threadIdx.x) >> 6;
  if (node >= n) return;
  int beg = offs[node], end = offs[node + 1];
  float acc = 0.f;
  for (int b0 = beg; b0 < end; b0 += 64) {
    int m = end - b0; if (m > 64) m = 64;
    int sl = 0; float wl = 0.f;
    if (lane < m) { sl = ssrc[b0 + lane]; wl = dinv[sl]; }
    for (int k = 0; k < m; ++k) {
      int s = __shfl(sl, k, 64);
      float w = __shfl(wl, k, 64);
      if (lane < F) acc += x[(size_t)s * F + lane] * w;
    }
  }
  if (lane < F) {
    float di = dinv[node];
    acc = (acc + x[(size_t)node * F + lane] * di) * di;
    out[(size_t)node * F + lane] = acc;
  }
}

__global__ void aggregate128_kernel(const float* __restrict__ x, const int* __restrict__ ssrc,
                                    const int* __restrict__ offs, const float* __restrict__ dinv,
                                    float* __restrict__ out, int n) {
  int lane = threadIdx.x & 63;
  int node = (blockIdx.x * blockDim.x + threadIdx.x) >> 6;
  if (node >= n) return;
  int beg = offs[node], end = offs[node + 1];
  float2 acc; acc.x = 0.f; acc.y = 0.f;
  const float2* x2 = (const float2*)x;
  for (int b0 = beg; b0 < end; b0 += 64) {
    int m = end - b0; if (m > 64) m = 64;
    int sl = 0; float wl = 0.f;
    if (lane < m) { sl = ssrc[b0 + lane]; wl = dinv[sl]; }
    for (int k = 0; k < m; ++k) {
      int s = __shfl(sl, k, 64);
      float w = __shfl(wl, k, 64);
      float2 v = x2[(size_t)s * 64 + lane];
      acc.x += v.x * w; acc.y += v.y * w;
    }
  }
  float di = dinv[node];
  float2 vi = x2[(size_t)node * 64 + lane];
  acc.x = (acc.x + vi.x * di) * di;
  acc.y = (acc.y + vi.y * di) * di;
  ((float2*)out)[(size_t)node * 64 + lane] = acc;
}

// ---------------- transform ----------------
template<int KIN, int NPB>
__global__ __launch_bounds__(128) void transform_relu_kernel(
    const float* __restrict__ in, const float* __restrict__ W,
    const float* __restrict__ bias, float* __restrict__ out, int n) {
  constexpr int KT = (KIN > 64) ? 64 : KIN;
  __shared__ float Ws[KT * 128];
  __shared__ float rowsT[KIN * NPB];
  const int f = threadIdx.x;
  const int base = blockIdx.x * NPB;

  for (int i = f; i < NPB * KIN; i += 128) {
    int j = i / KIN, k = i - j * KIN;
    int node = base + j;
    rowsT[k * NPB + j] = (node < n) ? in[(size_t)node * KIN + k] : 0.f;
  }

  float acc[NPB];
  #pragma unroll
  for (int j = 0; j < NPB; ++j) acc[j] = 0.f;

  for (int k0 = 0; k0 < KIN; k0 += KT) {
    __syncthreads();
    int kt = KIN - k0; if (kt > KT) kt = KT;
    for (int i = f; i < kt * 128; i += 128) Ws[i] = W[(size_t)k0 * 128 + i];
    __syncthreads();
    for (int k = 0; k < kt; ++k) {
      float w = Ws[k * 128 + f];
      const float4* rt = (const float4*)&rowsT[(k0 + k) * NPB];
      #pragma unroll
      for (int j4 = 0; j4 < NPB / 4; ++j4) {
        float4 r = rt[j4];
        acc[j4 * 4 + 0] += r.x * w;
        acc[j4 * 4 + 1] += r.y * w;
        acc[j4 * 4 + 2] += r.z * w;
        acc[j4 * 4 + 3] += r.w * w;
      }
    }
  }
  float bv = bias[f];
  #pragma unroll
  for (int j = 0; j < NPB; ++j) {
    int node = base + j;
    if (node < n) {
      float v = acc[j] + bv;
      out[(size_t)node * 128 + f] = v > 0.f ? v : 0.f;
    }
  }
}

// ---------------- segment starts from sorted batch ----------------
// start[g] = first node index with batch >= g;  start[G] = n
__global__ void seg_starts_kernel(const int* __restrict__ batch, int* __restrict__ start,
                                  int n, int G) {
  int i = blockIdx.x * blockDim.x + threadIdx.x;
  if (i >= n) return;
  int b = batch[i];
  if (i == 0) {
    for (int g = 0; g <= b; ++g) start[g] = 0;
  } else {
    int pb = batch[i - 1];
    for (int g = pb + 1; g <= b; ++g) start[g] = i;
  }
  if (i == n - 1) {
    for (int g = b + 1; g <= G; ++g) start[g] = n;
  }
}

// ---------------- segmented mean-pool (no atomics; batch sorted) ----------------
__global__ __launch_bounds__(512) void pool_seg_kernel(const float* __restrict__ h,
                                                       const int* __restrict__ start,
                                                       float* __restrict__ mean) {
  int g = blockIdx.x;
  int t = threadIdx.x;
  int f = t & 127, r = t >> 7;  // 4 node-rows in flight
  int beg = start[g], end = start[g + 1];
  float acc = 0.f;
  for (int i = beg + r; i < end; i += 4)
    acc += h[(size_t)i * 128 + f];
  __shared__ float red[4][128];
  red[r][f] = acc;
  __syncthreads();
  if (r == 0) {
    float s = red[0][f] + red[1][f] + red[2][f] + red[3][f];
    float c = (float)(end - beg);
    mean[(size_t)g * 128 + f] = s / fmaxf(c, 1.f);
  }
}

// ---------------- final FC + 3 heads ----------------
__global__ __launch_bounds__(128) void fc_heads_kernel(
    const float* __restrict__ pe, const float* __restrict__ le,
    const float* __restrict__ Wfc, const float* __restrict__ bfc,
    const float* __restrict__ Wpkd, const float* __restrict__ bpkd,
    const float* __restrict__ Wpki, const float* __restrict__ bpki,
    const float* __restrict__ Wba, const float* __restrict__ bba,
    float* __restrict__ out, int G) {
  int g = blockIdx.x, f = threadIdx.x;
  __shared__ float comb[256];
  __shared__ float cbuf[128];
  comb[f]       = pe[(size_t)g * 128 + f];
  comb[128 + f] = le[(size_t)g * 128 + f];
  __syncthreads();
  float acc = bfc[f];
  for (int k = 0; k < 256; ++k) acc += comb[k] * Wfc[(size_t)k * 128 + f];
  cbuf[f] = fmaxf(acc, 0.f);
  __syncthreads();
  if (f < 64) {
    const float* Wh[3] = {Wpkd, Wpki, Wba};
    const float* bh[3] = {bpkd, bpki, bba};
    #pragma unroll
    for (int hd = 0; hd < 3; ++hd) {
      float v = cbuf[f] * Wh[hd][f] + cbuf[f + 64] * Wh[hd][f + 64];
      #pragma unroll
      for (int d = 32; d; d >>= 1) v += __shfl_xor(v, d, 64);
      if (f == 0) out[(size_t)hd * G + g] = v + bh[hd][0];
    }
  }
}

// ============================================================================
static inline size_t alignUp(size_t x, size_t a) { return (x + a - 1) / a * a; }

extern "C" void kernel_launch(void* const* d_in, const int* in_sizes, int n_in,
                              void* d_out, int out_size, void* d_ws, size_t ws_size,
                              hipStream_t stream) {
  const float* px     = (const float*)d_in[0];
  const int*   pei    = (const int*)d_in[1];
  const int*   pbatch = (const int*)d_in[2];
  const float* lx     = (const float*)d_in[3];
  const int*   lei    = (const int*)d_in[4];
  const int*   lbatch = (const int*)d_in[5];
  const float* Wp1 = (const float*)d_in[7],  *bp1 = (const float*)d_in[8];
  const float* Wp2 = (const float*)d_in[9],  *bp2 = (const float*)d_in[10];
  const float* Wl1 = (const float*)d_in[11], *bl1 = (const float*)d_in[12];
  const float* Wl2 = (const float*)d_in[13], *bl2 = (const float*)d_in[14];
  const float* Wfc = (const float*)d_in[15], *bfc = (const float*)d_in[16];
  const float* Wpkd = (const float*)d_in[17], *bpkd = (const float*)d_in[18];
  const float* Wpki = (const float*)d_in[19], *bpki = (const float*)d_in[20];
  const float* Wba  = (const float*)d_in[21], *bba  = (const float*)d_in[22];
  float* out = (float*)d_out;

  const int Np = in_sizes[0] / 23, Ep = in_sizes[1] / 2;
  const int Nl = in_sizes[3] / 4,  El = in_sizes[4] / 2;
  const int G  = out_size / 3;

  // ---- workspace layout ----
  char* base = (char*)d_ws;
  size_t off = 0;
  auto alloc = [&](size_t bytes) -> void* {
    void* p = base + off;
    off = alignUp(off + bytes, 256);
    return p;
  };
  // zero zone (single memset per call): degree counts + scatter cursors only
  size_t zero_beg = off;
  int*   degcnt_p = (int*)alloc((size_t)Np * 4);
  int*   cursor_p = (int*)alloc((size_t)Np * 4);
  int*   degcnt_l = (int*)alloc((size_t)Nl * 4);
  int*   cursor_l = (int*)alloc((size_t)Nl * 4);
  size_t zero_end = off;
  // non-zeroed
  int*   offs_p  = (int*)alloc((size_t)(Np + 1) * 4);
  int*   offs_l  = (int*)alloc((size_t)(Nl + 1) * 4);
  int*   start_p = (int*)alloc((size_t)(G + 1) * 4);
  int*   start_l = (int*)alloc((size_t)(G + 1) * 4);
  float* dinv_p  = (float*)alloc((size_t)Np * 4);
  float* dinv_l  = (float*)alloc((size_t)Nl * 4);
  int*   ssrc_p  = (int*)alloc((size_t)Ep * 4);
  int*   ssrc_l  = (int*)alloc((size_t)El * 4);
  float* pe_mean = (float*)alloc((size_t)G * 128 * 4);
  float* le_mean = (float*)alloc((size_t)G * 128 * 4);
  float* bufA_p  = (float*)alloc((size_t)Np * 128 * 4);
  float* bufB_p  = (float*)alloc((size_t)Np * 128 * 4);
  float* bufA_l  = (float*)alloc((size_t)Nl * 128 * 4);
  float* bufB_l  = (float*)alloc((size_t)Nl * 128 * 4);
  if (off > ws_size) return;

  hipMemsetAsync(base + zero_beg, 0, zero_end - zero_beg, stream);

  const int* psrc = pei;
  const int* pdst = pei + Ep;
  const int* lsrc = lei;
  const int* ldst = lei + El;

  // ---- CSR build ----
  count_deg_kernel<<<(Ep + 255) / 256, 256, 0, stream>>>(pdst, degcnt_p, Ep);
  count_deg_kernel<<<(El + 255) / 256, 256, 0, stream>>>(ldst, degcnt_l, El);
  dinv_kernel<<<(Np + 255) / 256, 256, 0, stream>>>(degcnt_p, dinv_p, Np);
  dinv_kernel<<<(Nl + 255) / 256, 256, 0, stream>>>(degcnt_l, dinv_l, Nl);
  exscan_kernel<<<1, 1024, 0, stream>>>(degcnt_p, offs_p, Np);
  exscan_kernel<<<1, 1024, 0, stream>>>(degcnt_l, offs_l, Nl);
  scatter_kernel<<<(Ep + 255) / 256, 256, 0, stream>>>(psrc, pdst, offs_p, cursor_p, ssrc_p, Ep);
  scatter_kernel<<<(El + 255) / 256, 256, 0, stream>>>(lsrc, ldst, offs_l, cursor_l, ssrc_l, El);

  // segment boundaries for pooling (independent of CSR)
  seg_starts_kernel<<<(Np + 255) / 256, 256, 0, stream>>>(pbatch, start_p, Np, G);
  seg_starts_kernel<<<(Nl + 255) / 256, 256, 0, stream>>>(lbatch, start_l, Nl, G);

  // ---- protein GNN ----
  aggregate_small_kernel<23><<<(Np + 3) / 4, 256, 0, stream>>>(px, ssrc_p, offs_p, dinv_p, bufB_p, Np);
  transform_relu_kernel<23, 16><<<(Np + 15) / 16, 128, 0, stream>>>(bufB_p, Wp1, bp1, bufA_p, Np);
  aggregate128_kernel<<<(Np + 3) / 4, 256, 0, stream>>>(bufA_p, ssrc_p, offs_p, dinv_p, bufB_p, Np);
  transform_relu_kernel<128, 16><<<(Np + 15) / 16, 128, 0, stream>>>(bufB_p, Wp2, bp2, bufA_p, Np);

  // ---- ligand GNN ----
  aggregate_small_kernel<4><<<(Nl + 3) / 4, 256, 0, stream>>>(lx, ssrc_l, offs_l, dinv_l, bufB_l, Nl);
  transform_relu_kernel<4, 16><<<(Nl + 15) / 16, 128, 0, stream>>>(bufB_l, Wl1, bl1, bufA_l, Nl);
  aggregate128_kernel<<<(Nl + 3) / 4, 256, 0, stream>>>(bufA_l, ssrc_l, offs_l, dinv_l, bufB_l, Nl);
  transform_relu_kernel<128, 16><<<(Nl + 15) / 16, 128, 0, stream>>>(bufB_l, Wl2, bl2, bufA_l, Nl);

  // ---- segmented mean pool ----
  pool_seg_kernel<<<G, 512, 0, stream>>>(bufA_p, start_p, pe_mean);
  pool_seg_kernel<<<G, 512, 0, stream>>>(bufA_l, start_l, le_mean);

  // ---- FC + heads ----
  fc_heads_kernel<<<G, 128, 0, stream>>>(pe_mean, le_mean, Wfc, bfc,
                                         Wpkd, bpkd, Wpki, bpki, Wba, bba, out, G);
}

// Round 3
// 721.094 us; speedup vs baseline: 1.8254x; 1.1715x over previous
//
#include <hip/hip_runtime.h>

// ============================================================================
// ProteinLigandGNN: 2x GCNConv (protein), 2x GCNConv (ligand), mean-pool,
// FC + 3 heads.  All f32.
//
// GCNConv: out = D^-1/2 (A+I) D^-1/2 (X W) + b  ==  (D^-1/2 (A+I) D^-1/2 X) W + b
// Aggregate FIRST (narrow feature space when possible), then transform.
// Edge aggregation uses CSR-by-dst built on device each call.
// Mean-pool: batch arrays are SORTED -> segmented reduction, zero atomics.
// CSR offsets: 3-phase hierarchical scan (R2: single-block scan was 160us,
// latency-bound at 0.16% occupancy).
// ============================================================================

#define SCAN_CHUNK 2048

// ---------------- degree / dinv ----------------
__global__ void count_deg_kernel(const int* __restrict__ dst, int* __restrict__ deg, int E) {
  int e = blockIdx.x * blockDim.x + threadIdx.x;
  if (e < E) atomicAdd(&deg[dst[e]], 1);
}

__global__ void dinv_kernel(const int* __restrict__ deg, float* __restrict__ dinv, int n) {
  int i = blockIdx.x * blockDim.x + threadIdx.x;
  if (i < n) dinv[i] = rsqrtf((float)(deg[i] + 1));  // +1 self-loop; always > 0
}

// ---------------- hierarchical scan: phase 1 (per-chunk sums) ----------------
__global__ __launch_bounds__(256) void blocksum_kernel(const int* __restrict__ cnt,
                                                       int* __restrict__ bsum, int n) {
  int b = blockIdx.x, t = threadIdx.x;
  int base = b * SCAN_CHUNK;
  int s = 0;
  for (int i = t; i < SCAN_CHUNK; i += 256) {
    int idx = base + i;
    if (idx < n) s += cnt[idx];
  }
  #pragma unroll
  for (int d = 32; d; d >>= 1) s += __shfl_down(s, d, 64);
  __shared__ int wt[4];
  int lane = t & 63, wid = t >> 6;
  if (lane == 0) wt[wid] = s;
  __syncthreads();
  if (t == 0) bsum[b] = wt[0] + wt[1] + wt[2] + wt[3];
}

// ---------------- phase 2: scan of block sums (nb <= 1024), boffs[nb]=total --
__global__ __launch_bounds__(1024) void exscan_small_kernel(const int* __restrict__ bsum,
                                                            int* __restrict__ boffs, int nb) {
  int t = threadIdx.x;
  int v = (t < nb) ? bsum[t] : 0;
  int lane = t & 63, wid = t >> 6;
  int inc = v;
  #pragma unroll
  for (int d = 1; d < 64; d <<= 1) {
    int u = __shfl_up(inc, d, 64);
    if (lane >= d) inc += u;
  }
  __shared__ int wt[16];
  if (lane == 63) wt[wid] = inc;
  __syncthreads();
  if (t < 16) {
    int w = wt[t];
    #pragma unroll
    for (int d = 1; d < 16; d <<= 1) {
      int u = __shfl_up(w, d, 64);
      if (t >= d) w += u;
    }
    wt[t] = w;
  }
  __syncthreads();
  int excl = (wid ? wt[wid - 1] : 0) + inc - v;
  if (t < nb) boffs[t] = excl;
  if (t == 0) boffs[nb] = wt[15];  // total
}

// ---------------- phase 3: in-block scan + apply block offset ----------------
__global__ __launch_bounds__(256) void scan_apply_kernel(const int* __restrict__ cnt,
                                                         const int* __restrict__ boffs,
                                                         int* __restrict__ offs, int n, int nb) {
  int b = blockIdx.x, t = threadIdx.x;
  int base = b * SCAN_CHUNK + t * 8;
  int v[8];
  int s = 0;
  #pragma unroll
  for (int j = 0; j < 8; ++j) {
    int idx = base + j;
    v[j] = (idx < n) ? cnt[idx] : 0;
    s += v[j];
  }
  int lane = t & 63, wid = t >> 6;
  int inc = s;
  #pragma unroll
  for (int d = 1; d < 64; d <<= 1) {
    int u = __shfl_up(inc, d, 64);
    if (lane >= d) inc += u;
  }
  __shared__ int wt[4];
  if (lane == 63) wt[wid] = inc;
  __syncthreads();
  int wadd = 0;
  for (int w = 0; w < wid; ++w) wadd += wt[w];
  int excl = boffs[b] + wadd + inc - s;
  #pragma unroll
  for (int j = 0; j < 8; ++j) {
    int idx = base + j;
    if (idx < n) offs[idx] = excl;
    excl += v[j];
  }
  if (b == 0 && t == 0) offs[n] = boffs[nb];
}

// ---------------- scatter edges into CSR ----------------
__global__ void scatter_kernel(const int* __restrict__ src, const int* __restrict__ dst,
                               const int* __restrict__ offs, int* __restrict__ cursor,
                               int* __restrict__ ssrc, int E) {
  int e = blockIdx.x * blockDim.x + threadIdx.x;
  if (e >= E) return;
  int d = dst[e];
  int pos = offs[d] + atomicAdd(&cursor[d], 1);
  ssrc[pos] = src[e];
}

// ---------------- aggregation ----------------
template<int F>
__global__ void aggregate_small_kernel(const float* __restrict__ x, const int* __restrict__ ssrc,
                                       const int* __restrict__ offs, const float* __restrict__ dinv,
                                       float* __restrict__ out, int n) {
  int lane = threadIdx.x & 63;
  int node = (blockIdx.x * blockDim.x + threadIdx.x) >> 6;
  if (node >= n) return;
  int beg = offs[node], end = offs[node + 1];
  float acc = 0.f;
  for (int b0 = beg; b0 < end; b0 += 64) {
    int m = end - b0; if (m > 64) m = 64;
    int sl = 0; float wl = 0.f;
    if (lane < m) { sl = ssrc[b0 + lane]; wl = dinv[sl]; }
    for (int k = 0; k < m; ++k) {
      int s = __shfl(sl, k, 64);
      float w = __shfl(wl, k, 64);
      if (lane < F) acc += x[(size_t)s * F + lane] * w;
    }
  }
  if (lane < F) {
    float di = dinv[node];
    acc = (acc + x[(size_t)node * F + lane] * di) * di;
    out[(size_t)node * F + lane] = acc;
  }
}

__global__ void aggregate128_kernel(const float* __restrict__ x, const int* __restrict__ ssrc,
                                    const int* __restrict__ offs, const float* __restrict__ dinv,
                                    float* __restrict__ out, int n) {
  int lane = threadIdx.x & 63;
  int node = (blockIdx.x * blockDim.x + threadIdx.x) >> 6;
  if (node >= n) return;
  int beg = offs[node], end = offs[node + 1];
  float2 acc; acc.x = 0.f; acc.y = 0.f;
  const float2* x2 = (const float2*)x;
  for (int b0 = beg; b0 < end; b0 += 64) {
    int m = end - b0; if (m > 64) m = 64;
    int sl = 0; float wl = 0.f;
    if (lane < m) { sl = ssrc[b0 + lane]; wl = dinv[sl]; }
    for (int k = 0; k < m; ++k) {
      int s = __shfl(sl, k, 64);
      float w = __shfl(wl, k, 64);
      float2 v = x2[(size_t)s * 64 + lane];
      acc.x += v.x * w; acc.y += v.y * w;
    }
  }
  float di = dinv[node];
  float2 vi = x2[(size_t)node * 64 + lane];
  acc.x = (acc.x + vi.x * di) * di;
  acc.y = (acc.y + vi.y * di) * di;
  ((float2*)out)[(size_t)node * 64 + lane] = acc;
}

// ---------------- transform ----------------
template<int KIN, int NPB>
__global__ __launch_bounds__(128) void transform_relu_kernel(
    const float* __restrict__ in, const float* __restrict__ W,
    const float* __restrict__ bias, float* __restrict__ out, int n) {
  constexpr int KT = (KIN > 64) ? 64 : KIN;
  __shared__ float Ws[KT * 128];
  __shared__ float rowsT[KIN * NPB];
  const int f = threadIdx.x;
  const int base = blockIdx.x * NPB;

  for (int i = f; i < NPB * KIN; i += 128) {
    int j = i / KIN, k = i - j * KIN;
    int node = base + j;
    rowsT[k * NPB + j] = (node < n) ? in[(size_t)node * KIN + k] : 0.f;
  }

  float acc[NPB];
  #pragma unroll
  for (int j = 0; j < NPB; ++j) acc[j] = 0.f;

  for (int k0 = 0; k0 < KIN; k0 += KT) {
    __syncthreads();
    int kt = KIN - k0; if (kt > KT) kt = KT;
    for (int i = f; i < kt * 128; i += 128) Ws[i] = W[(size_t)k0 * 128 + i];
    __syncthreads();
    for (int k = 0; k < kt; ++k) {
      float w = Ws[k * 128 + f];
      const float4* rt = (const float4*)&rowsT[(k0 + k) * NPB];
      #pragma unroll
      for (int j4 = 0; j4 < NPB / 4; ++j4) {
        float4 r = rt[j4];
        acc[j4 * 4 + 0] += r.x * w;
        acc[j4 * 4 + 1] += r.y * w;
        acc[j4 * 4 + 2] += r.z * w;
        acc[j4 * 4 + 3] += r.w * w;
      }
    }
  }
  float bv = bias[f];
  #pragma unroll
  for (int j = 0; j < NPB; ++j) {
    int node = base + j;
    if (node < n) {
      float v = acc[j] + bv;
      out[(size_t)node * 128 + f] = v > 0.f ? v : 0.f;
    }
  }
}

// ---------------- segment starts from sorted batch ----------------
__global__ void seg_starts_kernel(const int* __restrict__ batch, int* __restrict__ start,
                                  int n, int G) {
  int i = blockIdx.x * blockDim.x + threadIdx.x;
  if (i >= n) return;
  int b = batch[i];
  if (i == 0) {
    for (int g = 0; g <= b; ++g) start[g] = 0;
  } else {
    int pb = batch[i - 1];
    for (int g = pb + 1; g <= b; ++g) start[g] = i;
  }
  if (i == n - 1) {
    for (int g = b + 1; g <= G; ++g) start[g] = n;
  }
}

// ---------------- segmented mean-pool (no atomics; batch sorted) ----------------
__global__ __launch_bounds__(512) void pool_seg_kernel(const float* __restrict__ h,
                                                       const int* __restrict__ start,
                                                       float* __restrict__ mean) {
  int g = blockIdx.x;
  int t = threadIdx.x;
  int f = t & 127, r = t >> 7;
  int beg = start[g], end = start[g + 1];
  float acc = 0.f;
  for (int i = beg + r; i < end; i += 4)
    acc += h[(size_t)i * 128 + f];
  __shared__ float red[4][128];
  red[r][f] = acc;
  __syncthreads();
  if (r == 0) {
    float s = red[0][f] + red[1][f] + red[2][f] + red[3][f];
    float c = (float)(end - beg);
    mean[(size_t)g * 128 + f] = s / fmaxf(c, 1.f);
  }
}

// ---------------- final FC + 3 heads ----------------
__global__ __launch_bounds__(128) void fc_heads_kernel(
    const float* __restrict__ pe, const float* __restrict__ le,
    const float* __restrict__ Wfc, const float* __restrict__ bfc,
    const float* __restrict__ Wpkd, const float* __restrict__ bpkd,
    const float* __restrict__ Wpki, const float* __restrict__ bpki,
    const float* __restrict__ Wba, const float* __restrict__ bba,
    float* __restrict__ out, int G) {
  int g = blockIdx.x, f = threadIdx.x;
  __shared__ float comb[256];
  __shared__ float cbuf[128];
  comb[f]       = pe[(size_t)g * 128 + f];
  comb[128 + f] = le[(size_t)g * 128 + f];
  __syncthreads();
  float acc = bfc[f];
  for (int k = 0; k < 256; ++k) acc += comb[k] * Wfc[(size_t)k * 128 + f];
  cbuf[f] = fmaxf(acc, 0.f);
  __syncthreads();
  if (f < 64) {
    const float* Wh[3] = {Wpkd, Wpki, Wba};
    const float* bh[3] = {bpkd, bpki, bba};
    #pragma unroll
    for (int hd = 0; hd < 3; ++hd) {
      float v = cbuf[f] * Wh[hd][f] + cbuf[f + 64] * Wh[hd][f + 64];
      #pragma unroll
      for (int d = 32; d; d >>= 1) v += __shfl_xor(v, d, 64);
      if (f == 0) out[(size_t)hd * G + g] = v + bh[hd][0];
    }
  }
}

// ============================================================================
static inline size_t alignUp(size_t x, size_t a) { return (x + a - 1) / a * a; }

extern "C" void kernel_launch(void* const* d_in, const int* in_sizes, int n_in,
                              void* d_out, int out_size, void* d_ws, size_t ws_size,
                              hipStream_t stream) {
  const float* px     = (const float*)d_in[0];
  const int*   pei    = (const int*)d_in[1];
  const int*   pbatch = (const int*)d_in[2];
  const float* lx     = (const float*)d_in[3];
  const int*   lei    = (const int*)d_in[4];
  const int*   lbatch = (const int*)d_in[5];
  const float* Wp1 = (const float*)d_in[7],  *bp1 = (const float*)d_in[8];
  const float* Wp2 = (const float*)d_in[9],  *bp2 = (const float*)d_in[10];
  const float* Wl1 = (const float*)d_in[11], *bl1 = (const float*)d_in[12];
  const float* Wl2 = (const float*)d_in[13], *bl2 = (const float*)d_in[14];
  const float* Wfc = (const float*)d_in[15], *bfc = (const float*)d_in[16];
  const float* Wpkd = (const float*)d_in[17], *bpkd = (const float*)d_in[18];
  const float* Wpki = (const float*)d_in[19], *bpki = (const float*)d_in[20];
  const float* Wba  = (const float*)d_in[21], *bba  = (const float*)d_in[22];
  float* out = (float*)d_out;

  const int Np = in_sizes[0] / 23, Ep = in_sizes[1] / 2;
  const int Nl = in_sizes[3] / 4,  El = in_sizes[4] / 2;
  const int G  = out_size / 3;
  const int nb_p = (Np + SCAN_CHUNK - 1) / SCAN_CHUNK;
  const int nb_l = (Nl + SCAN_CHUNK - 1) / SCAN_CHUNK;

  // ---- workspace layout ----
  char* base = (char*)d_ws;
  size_t off = 0;
  auto alloc = [&](size_t bytes) -> void* {
    void* p = base + off;
    off = alignUp(off + bytes, 256);
    return p;
  };
  size_t zero_beg = off;
  int*   degcnt_p = (int*)alloc((size_t)Np * 4);
  int*   cursor_p = (int*)alloc((size_t)Np * 4);
  int*   degcnt_l = (int*)alloc((size_t)Nl * 4);
  int*   cursor_l = (int*)alloc((size_t)Nl * 4);
  size_t zero_end = off;
  int*   offs_p  = (int*)alloc((size_t)(Np + 1) * 4);
  int*   offs_l  = (int*)alloc((size_t)(Nl + 1) * 4);
  int*   bsum_p  = (int*)alloc((size_t)nb_p * 4);
  int*   boffs_p = (int*)alloc((size_t)(nb_p + 1) * 4);
  int*   bsum_l  = (int*)alloc((size_t)nb_l * 4);
  int*   boffs_l = (int*)alloc((size_t)(nb_l + 1) * 4);
  int*   start_p = (int*)alloc((size_t)(G + 1) * 4);
  int*   start_l = (int*)alloc((size_t)(G + 1) * 4);
  float* dinv_p  = (float*)alloc((size_t)Np * 4);
  float* dinv_l  = (float*)alloc((size_t)Nl * 4);
  int*   ssrc_p  = (int*)alloc((size_t)Ep * 4);
  int*   ssrc_l  = (int*)alloc((size_t)El * 4);
  float* pe_mean = (float*)alloc((size_t)G * 128 * 4);
  float* le_mean = (float*)alloc((size_t)G * 128 * 4);
  float* bufA_p  = (float*)alloc((size_t)Np * 128 * 4);
  float* bufB_p  = (float*)alloc((size_t)Np * 128 * 4);
  float* bufA_l  = (float*)alloc((size_t)Nl * 128 * 4);
  float* bufB_l  = (float*)alloc((size_t)Nl * 128 * 4);
  if (off > ws_size) return;

  hipMemsetAsync(base + zero_beg, 0, zero_end - zero_beg, stream);

  const int* psrc = pei;
  const int* pdst = pei + Ep;
  const int* lsrc = lei;
  const int* ldst = lei + El;

  // ---- CSR build ----
  count_deg_kernel<<<(Ep + 255) / 256, 256, 0, stream>>>(pdst, degcnt_p, Ep);
  count_deg_kernel<<<(El + 255) / 256, 256, 0, stream>>>(ldst, degcnt_l, El);
  dinv_kernel<<<(Np + 255) / 256, 256, 0, stream>>>(degcnt_p, dinv_p, Np);
  dinv_kernel<<<(Nl + 255) / 256, 256, 0, stream>>>(degcnt_l, dinv_l, Nl);
  // hierarchical scan (protein)
  blocksum_kernel<<<nb_p, 256, 0, stream>>>(degcnt_p, bsum_p, Np);
  exscan_small_kernel<<<1, 1024, 0, stream>>>(bsum_p, boffs_p, nb_p);
  scan_apply_kernel<<<nb_p, 256, 0, stream>>>(degcnt_p, boffs_p, offs_p, Np, nb_p);
  // hierarchical scan (ligand)
  blocksum_kernel<<<nb_l, 256, 0, stream>>>(degcnt_l, bsum_l, Nl);
  exscan_small_kernel<<<1, 1024, 0, stream>>>(bsum_l, boffs_l, nb_l);
  scan_apply_kernel<<<nb_l, 256, 0, stream>>>(degcnt_l, boffs_l, offs_l, Nl, nb_l);

  scatter_kernel<<<(Ep + 255) / 256, 256, 0, stream>>>(psrc, pdst, offs_p, cursor_p, ssrc_p, Ep);
  scatter_kernel<<<(El + 255) / 256, 256, 0, stream>>>(lsrc, ldst, offs_l, cursor_l, ssrc_l, El);

  seg_starts_kernel<<<(Np + 255) / 256, 256, 0, stream>>>(pbatch, start_p, Np, G);
  seg_starts_kernel<<<(Nl + 255) / 256, 256, 0, stream>>>(lbatch, start_l, Nl, G);

  // ---- protein GNN ----
  aggregate_small_kernel<23><<<(Np + 3) / 4, 256, 0, stream>>>(px, ssrc_p, offs_p, dinv_p, bufB_p, Np);
  transform_relu_kernel<23, 16><<<(Np + 15) / 16, 128, 0, stream>>>(bufB_p, Wp1, bp1, bufA_p, Np);
  aggregate128_kernel<<<(Np + 3) / 4, 256, 0, stream>>>(bufA_p, ssrc_p, offs_p, dinv_p, bufB_p, Np);
  transform_relu_kernel<128, 16><<<(Np + 15) / 16, 128, 0, stream>>>(bufB_p, Wp2, bp2, bufA_p, Np);

  // ---- ligand GNN ----
  aggregate_small_kernel<4><<<(Nl + 3) / 4, 256, 0, stream>>>(lx, ssrc_l, offs_l, dinv_l, bufB_l, Nl);
  transform_relu_kernel<4, 16><<<(Nl + 15) / 16, 128, 0, stream>>>(bufB_l, Wl1, bl1, bufA_l, Nl);
  aggregate128_kernel<<<(Nl + 3) / 4, 256, 0, stream>>>(bufA_l, ssrc_l, offs_l, dinv_l, bufB_l, Nl);
  transform_relu_kernel<128, 16><<<(Nl + 15) / 16, 128, 0, stream>>>(bufB_l, Wl2, bl2, bufA_l, Nl);

  // ---- segmented mean pool ----
  pool_seg_kernel<<<G, 512, 0, stream>>>(bufA_p, start_p, pe_mean);
  pool_seg_kernel<<<G, 512, 0, stream>>>(bufA_l, start_l, le_mean);

  // ---- FC + heads ----
  fc_heads_kernel<<<G, 128, 0, stream>>>(pe_mean, le_mean, Wfc, bfc,
                                         Wpkd, bpkd, Wpki, bpki, Wba, bba, out, G);
}

// Round 4
// 618.341 us; speedup vs baseline: 2.1287x; 1.1662x over previous
//
#include <hip/hip_runtime.h>

// ============================================================================
// ProteinLigandGNN: 2x GCNConv (protein), 2x GCNConv (ligand), mean-pool,
// FC + 3 heads.
//
// GCNConv: out = D^-1/2 (A+I) D^-1/2 (X W) + b  ==  (D^-1/2 (A+I) D^-1/2 X) W + b
// Aggregate FIRST (narrow feature space when possible), then transform.
// R3: protein h1 stored bf16 (halves the 820MB logical gather of layer-2 agg,
//     which showed 415MB HBM fetch / 132us); lane-group layer-1 aggregation;
//     protein+ligand stages fused into single launches (26 -> 14 dispatches).
// ============================================================================

typedef unsigned short ushort_t;

#define SCAN_CHUNK 2048

static __device__ inline ushort_t f2bf(float f) {  // RNE f32->bf16
  unsigned u = __float_as_uint(f);
  unsigned r = (u + 0x7FFFu + ((u >> 16) & 1u)) >> 16;
  return (ushort_t)r;
}
static __device__ inline float bf2f(ushort_t b) {
  return __uint_as_float((unsigned)b << 16);
}

// ---------------- fused degree count (both graphs) ----------------
__global__ void count_deg2_kernel(const int* __restrict__ dstP, int Ep, int* __restrict__ degP,
                                  const int* __restrict__ dstL, int El, int* __restrict__ degL) {
  int e = blockIdx.x * blockDim.x + threadIdx.x;
  if (e < Ep) atomicAdd(&degP[dstP[e]], 1);
  else if (e < Ep + El) atomicAdd(&degL[dstL[e - Ep]], 1);
}

// ---------------- fused per-node prep: dinv + segment starts ----------------
__device__ inline void node_prep_dev(const int* deg, float* dinv, const int* batch,
                                     int* start, int i, int n, int G) {
  dinv[i] = rsqrtf((float)(deg[i] + 1));
  int b = batch[i];
  if (i == 0) { for (int g = 0; g <= b; ++g) start[g] = 0; }
  else { int pb = batch[i - 1]; for (int g = pb + 1; g <= b; ++g) start[g] = i; }
  if (i == n - 1) { for (int g = b + 1; g <= G; ++g) start[g] = n; }
}

__global__ void node_prep_kernel(const int* __restrict__ degP, float* __restrict__ dinvP,
                                 const int* __restrict__ batchP, int* __restrict__ startP, int nP,
                                 const int* __restrict__ degL, float* __restrict__ dinvL,
                                 const int* __restrict__ batchL, int* __restrict__ startL, int nL,
                                 int G) {
  int i = blockIdx.x * blockDim.x + threadIdx.x;
  if (i < nP) node_prep_dev(degP, dinvP, batchP, startP, i, nP, G);
  int j = i - nP;
  if (j >= 0 && j < nL) node_prep_dev(degL, dinvL, batchL, startL, j, nL, G);
}

// ---------------- hierarchical scan ----------------
__device__ inline void blocksum_dev(const int* cnt, int* bsum, int n, int b) {
  int t = threadIdx.x;
  int base = b * SCAN_CHUNK;
  int s = 0;
  for (int i = t; i < SCAN_CHUNK; i += 256) {
    int idx = base + i;
    if (idx < n) s += cnt[idx];
  }
  #pragma unroll
  for (int d = 32; d; d >>= 1) s += __shfl_down(s, d, 64);
  __shared__ int wt[4];
  int lane = t & 63, wid = t >> 6;
  if (lane == 0) wt[wid] = s;
  __syncthreads();
  if (t == 0) bsum[b] = wt[0] + wt[1] + wt[2] + wt[3];
}

__global__ __launch_bounds__(256) void blocksum2_kernel(
    const int* __restrict__ cntP, int nP, int nbP, int* __restrict__ bsumP,
    const int* __restrict__ cntL, int nL, int* __restrict__ bsumL) {
  int b = blockIdx.x;
  if (b < nbP) blocksum_dev(cntP, bsumP, nP, b);
  else blocksum_dev(cntL, bsumL, nL, b - nbP);
}

__device__ inline void exscan_small_dev(const int* bsum, int* boffs, int nb) {
  int t = threadIdx.x;
  int v = (t < nb) ? bsum[t] : 0;
  int lane = t & 63, wid = t >> 6;
  int inc = v;
  #pragma unroll
  for (int d = 1; d < 64; d <<= 1) {
    int u = __shfl_up(inc, d, 64);
    if (lane >= d) inc += u;
  }
  __shared__ int wt[16];
  if (lane == 63) wt[wid] = inc;
  __syncthreads();
  if (t < 16) {
    int w = wt[t];
    #pragma unroll
    for (int d = 1; d < 16; d <<= 1) {
      int u = __shfl_up(w, d, 64);
      if (t >= d) w += u;
    }
    wt[t] = w;
  }
  __syncthreads();
  int excl = (wid ? wt[wid - 1] : 0) + inc - v;
  if (t < nb) boffs[t] = excl;
  if (t == 0) boffs[nb] = wt[15];
}

__global__ __launch_bounds__(1024) void exscan2_kernel(const int* __restrict__ bsumP,
                                                       int* __restrict__ boffsP, int nbP,
                                                       const int* __restrict__ bsumL,
                                                       int* __restrict__ boffsL, int nbL) {
  if (blockIdx.x == 0) exscan_small_dev(bsumP, boffsP, nbP);
  else exscan_small_dev(bsumL, boffsL, nbL);
}

__device__ inline void scan_apply_dev(const int* cnt, const int* boffs, int* offs,
                                      int n, int nb, int b) {
  int t = threadIdx.x;
  int base = b * SCAN_CHUNK + t * 8;
  int v[8];
  int s = 0;
  #pragma unroll
  for (int j = 0; j < 8; ++j) {
    int idx = base + j;
    v[j] = (idx < n) ? cnt[idx] : 0;
    s += v[j];
  }
  int lane = t & 63, wid = t >> 6;
  int inc = s;
  #pragma unroll
  for (int d = 1; d < 64; d <<= 1) {
    int u = __shfl_up(inc, d, 64);
    if (lane >= d) inc += u;
  }
  __shared__ int wt[4];
  if (lane == 63) wt[wid] = inc;
  __syncthreads();
  int wadd = 0;
  for (int w = 0; w < wid; ++w) wadd += wt[w];
  int excl = boffs[b] + wadd + inc - s;
  #pragma unroll
  for (int j = 0; j < 8; ++j) {
    int idx = base + j;
    if (idx < n) offs[idx] = excl;
    excl += v[j];
  }
  if (b == 0 && t == 0) offs[n] = boffs[nb];
}

__global__ __launch_bounds__(256) void scan_apply2_kernel(
    const int* __restrict__ cntP, const int* __restrict__ boffsP, int* __restrict__ offsP,
    int nP, int nbP,
    const int* __restrict__ cntL, const int* __restrict__ boffsL, int* __restrict__ offsL,
    int nL, int nbL) {
  int b = blockIdx.x;
  if (b < nbP) scan_apply_dev(cntP, boffsP, offsP, nP, nbP, b);
  else scan_apply_dev(cntL, boffsL, offsL, nL, nbL, b - nbP);
}

// ---------------- fused scatter ----------------
__global__ void scatter2_kernel(const int* __restrict__ srcP, const int* __restrict__ dstP,
                                const int* __restrict__ offsP, int* __restrict__ curP,
                                int* __restrict__ ssrcP, int Ep,
                                const int* __restrict__ srcL, const int* __restrict__ dstL,
                                const int* __restrict__ offsL, int* __restrict__ curL,
                                int* __restrict__ ssrcL, int El) {
  int e = blockIdx.x * blockDim.x + threadIdx.x;
  if (e < Ep) {
    int d = dstP[e];
    ssrcP[offsP[d] + atomicAdd(&curP[d], 1)] = srcP[e];
  } else if (e < Ep + El) {
    int e2 = e - Ep;
    int d = dstL[e2];
    ssrcL[offsL[d] + atomicAdd(&curL[d], 1)] = srcL[e2];
  }
}

// ---------------- layer-1 aggregation: lane-grouped (LPG lanes per edge) ----
template<int F, int LPG>
__device__ inline void agg_small_dev(const float* __restrict__ x, const int* __restrict__ ssrc,
                                     const int* __restrict__ offs, const float* __restrict__ dinv,
                                     float* __restrict__ out, int node, int n) {
  if (node >= n) return;
  constexpr int G = 64 / LPG;  // edges in flight per wave
  int lane = threadIdx.x & 63;
  int grp = lane / LPG, l = lane % LPG;
  int beg = offs[node], end = offs[node + 1];
  float acc = 0.f;
  for (int b0 = beg; b0 < end; b0 += 64) {
    int m = end - b0; if (m > 64) m = 64;
    int sl = 0; float wl = 0.f;
    if (lane < m) { sl = ssrc[b0 + lane]; wl = dinv[sl]; }
    for (int k = 0; k < m; k += G) {
      int idx = k + grp;                 // <= 63 always (G divides 64)
      int s = __shfl(sl, idx, 64);
      float w = __shfl(wl, idx, 64);     // 0 for idx >= m
      if (l < F) acc += x[(size_t)s * F + l] * w;
    }
  }
  #pragma unroll
  for (int d = LPG; d < 64; d <<= 1) acc += __shfl_xor(acc, d, 64);
  if (grp == 0 && l < F) {
    float di = dinv[node];
    acc = (acc + x[(size_t)node * F + l] * di) * di;
    out[(size_t)node * F + l] = acc;
  }
}

__global__ void agg1_both_kernel(const float* __restrict__ xP, const int* __restrict__ ssrcP,
                                 const int* __restrict__ offsP, const float* __restrict__ dinvP,
                                 float* __restrict__ outP, int nP, int nblkP,
                                 const float* __restrict__ xL, const int* __restrict__ ssrcL,
                                 const int* __restrict__ offsL, const float* __restrict__ dinvL,
                                 float* __restrict__ outL, int nL) {
  int wave_in_blk = threadIdx.x >> 6;
  if ((int)blockIdx.x < nblkP) {
    int node = blockIdx.x * 4 + wave_in_blk;
    agg_small_dev<23, 32>(xP, ssrcP, offsP, dinvP, outP, node, nP);
  } else {
    int node = (blockIdx.x - nblkP) * 4 + wave_in_blk;
    agg_small_dev<4, 4>(xL, ssrcL, offsL, dinvL, outL, node, nL);
  }
}

// ---------------- layer-2 aggregation (128 features) ----------------
// protein: bf16 table (halves gather bytes); ligand: f32 (L2-resident)
__device__ inline void agg128_bf_dev(const ushort_t* __restrict__ x, const int* __restrict__ ssrc,
                                     const int* __restrict__ offs, const float* __restrict__ dinv,
                                     float* __restrict__ out, int node, int n) {
  if (node >= n) return;
  int lane = threadIdx.x & 63;
  int beg = offs[node], end = offs[node + 1];
  float ax = 0.f, ay = 0.f;
  const ushort2* x2 = (const ushort2*)x;  // row = 64 ushort2 (256B)
  for (int b0 = beg; b0 < end; b0 += 64) {
    int m = end - b0; if (m > 64) m = 64;
    int sl = 0; float wl = 0.f;
    if (lane < m) { sl = ssrc[b0 + lane]; wl = dinv[sl]; }
    for (int k = 0; k < m; ++k) {
      int s = __shfl(sl, k, 64);
      float w = __shfl(wl, k, 64);
      ushort2 v = x2[(size_t)s * 64 + lane];
      ax += bf2f(v.x) * w;
      ay += bf2f(v.y) * w;
    }
  }
  float di = dinv[node];
  ushort2 vi = x2[(size_t)node * 64 + lane];
  ax = (ax + bf2f(vi.x) * di) * di;
  ay = (ay + bf2f(vi.y) * di) * di;
  ((float2*)out)[(size_t)node * 64 + lane] = make_float2(ax, ay);
}

__device__ inline void agg128_f32_dev(const float* __restrict__ x, const int* __restrict__ ssrc,
                                      const int* __restrict__ offs, const float* __restrict__ dinv,
                                      float* __restrict__ out, int node, int n) {
  if (node >= n) return;
  int lane = threadIdx.x & 63;
  int beg = offs[node], end = offs[node + 1];
  float2 acc; acc.x = 0.f; acc.y = 0.f;
  const float2* x2 = (const float2*)x;
  for (int b0 = beg; b0 < end; b0 += 64) {
    int m = end - b0; if (m > 64) m = 64;
    int sl = 0; float wl = 0.f;
    if (lane < m) { sl = ssrc[b0 + lane]; wl = dinv[sl]; }
    for (int k = 0; k < m; ++k) {
      int s = __shfl(sl, k, 64);
      float w = __shfl(wl, k, 64);
      float2 v = x2[(size_t)s * 64 + lane];
      acc.x += v.x * w; acc.y += v.y * w;
    }
  }
  float di = dinv[node];
  float2 vi = x2[(size_t)node * 64 + lane];
  acc.x = (acc.x + vi.x * di) * di;
  acc.y = (acc.y + vi.y * di) * di;
  ((float2*)out)[(size_t)node * 64 + lane] = acc;
}

__global__ void agg2_both_kernel(const ushort_t* __restrict__ xP, const int* __restrict__ ssrcP,
                                 const int* __restrict__ offsP, const float* __restrict__ dinvP,
                                 float* __restrict__ outP, int nP, int nblkP,
                                 const float* __restrict__ xL, const int* __restrict__ ssrcL,
                                 const int* __restrict__ offsL, const float* __restrict__ dinvL,
                                 float* __restrict__ outL, int nL) {
  int wave_in_blk = threadIdx.x >> 6;
  if ((int)blockIdx.x < nblkP) {
    int node = blockIdx.x * 4 + wave_in_blk;
    agg128_bf_dev(xP, ssrcP, offsP, dinvP, outP, node, nP);
  } else {
    int node = (blockIdx.x - nblkP) * 4 + wave_in_blk;
    agg128_f32_dev(xL, ssrcL, offsL, dinvL, outL, node, nL);
  }
}

// ---------------- transform: out[n][128] = relu(in[n][KIN] @ W + b) ----------------
__device__ inline void store_out(float* p, float v) { *p = v; }
__device__ inline void store_out(ushort_t* p, float v) { *p = f2bf(v); }

template<int KIN, int NPB, typename OutT>
__device__ inline void transform_dev(float* smem, const float* __restrict__ in,
                                     const float* __restrict__ W, const float* __restrict__ bias,
                                     OutT* __restrict__ out, int n, int blk) {
  constexpr int KT = (KIN > 64) ? 64 : KIN;
  float* Ws = smem;                 // KT*128
  float* rowsT = smem + KT * 128;   // KIN*NPB, [k][j]
  const int f = threadIdx.x;
  const int base = blk * NPB;

  for (int i = f; i < NPB * KIN; i += 128) {
    int j = i / KIN, k = i - j * KIN;
    int node = base + j;
    rowsT[k * NPB + j] = (node < n) ? in[(size_t)node * KIN + k] : 0.f;
  }

  float acc[NPB];
  #pragma unroll
  for (int j = 0; j < NPB; ++j) acc[j] = 0.f;

  for (int k0 = 0; k0 < KIN; k0 += KT) {
    __syncthreads();
    int kt = KIN - k0; if (kt > KT) kt = KT;
    for (int i = f; i < kt * 128; i += 128) Ws[i] = W[(size_t)k0 * 128 + i];
    __syncthreads();
    for (int k = 0; k < kt; ++k) {
      float w = Ws[k * 128 + f];
      const float4* rt = (const float4*)&rowsT[(k0 + k) * NPB];
      #pragma unroll
      for (int j4 = 0; j4 < NPB / 4; ++j4) {
        float4 r = rt[j4];
        acc[j4 * 4 + 0] += r.x * w;
        acc[j4 * 4 + 1] += r.y * w;
        acc[j4 * 4 + 2] += r.z * w;
        acc[j4 * 4 + 3] += r.w * w;
      }
    }
  }
  float bv = bias[f];
  #pragma unroll
  for (int j = 0; j < NPB; ++j) {
    int node = base + j;
    if (node < n) {
      float v = acc[j] + bv;
      store_out(&out[(size_t)node * 128 + f], v > 0.f ? v : 0.f);
    }
  }
}

// layer-1 transforms: protein KIN=23 -> bf16 out, ligand KIN=4 -> f32 out
__global__ __launch_bounds__(128) void transform1_both_kernel(
    const float* __restrict__ inP, const float* __restrict__ WP, const float* __restrict__ bP,
    ushort_t* __restrict__ outP, int nP, int nblkP,
    const float* __restrict__ inL, const float* __restrict__ WL, const float* __restrict__ bL,
    float* __restrict__ outL, int nL) {
  __shared__ float smem[23 * 128 + 23 * 16];  // max of the two paths
  if ((int)blockIdx.x < nblkP)
    transform_dev<23, 16, ushort_t>(smem, inP, WP, bP, outP, nP, blockIdx.x);
  else
    transform_dev<4, 16, float>(smem, inL, WL, bL, outL, nL, blockIdx.x - nblkP);
}

// layer-2 transforms: both KIN=128, f32 out
__global__ __launch_bounds__(128) void transform2_both_kernel(
    const float* __restrict__ inP, const float* __restrict__ WP, const float* __restrict__ bP,
    float* __restrict__ outP, int nP, int nblkP,
    const float* __restrict__ inL, const float* __restrict__ WL, const float* __restrict__ bL,
    float* __restrict__ outL, int nL) {
  __shared__ float smem[64 * 128 + 128 * 16];  // 40KB
  if ((int)blockIdx.x < nblkP)
    transform_dev<128, 16, float>(smem, inP, WP, bP, outP, nP, blockIdx.x);
  else
    transform_dev<128, 16, float>(smem, inL, WL, bL, outL, nL, blockIdx.x - nblkP);
}

// ---------------- segmented mean-pool (both graphs) ----------------
__device__ inline void pool_dev(const float* __restrict__ h, const int* __restrict__ start,
                                float* __restrict__ mean, int g) {
  int t = threadIdx.x;
  int f = t & 127, r = t >> 7;
  int beg = start[g], end = start[g + 1];
  float acc = 0.f;
  for (int i = beg + r; i < end; i += 4)
    acc += h[(size_t)i * 128 + f];
  __shared__ float red[4][128];
  red[r][f] = acc;
  __syncthreads();
  if (r == 0) {
    float s = red[0][f] + red[1][f] + red[2][f] + red[3][f];
    float c = (float)(end - beg);
    mean[(size_t)g * 128 + f] = s / fmaxf(c, 1.f);
  }
}

__global__ __launch_bounds__(512) void pool_both_kernel(
    const float* __restrict__ hP, const int* __restrict__ startP, float* __restrict__ meanP,
    const float* __restrict__ hL, const int* __restrict__ startL, float* __restrict__ meanL,
    int G) {
  int g = blockIdx.x;
  if (g < G) pool_dev(hP, startP, meanP, g);
  else pool_dev(hL, startL, meanL, g - G);
}

// ---------------- final FC + 3 heads ----------------
__global__ __launch_bounds__(128) void fc_heads_kernel(
    const float* __restrict__ pe, const float* __restrict__ le,
    const float* __restrict__ Wfc, const float* __restrict__ bfc,
    const float* __restrict__ Wpkd, const float* __restrict__ bpkd,
    const float* __restrict__ Wpki, const float* __restrict__ bpki,
    const float* __restrict__ Wba, const float* __restrict__ bba,
    float* __restrict__ out, int G) {
  int g = blockIdx.x, f = threadIdx.x;
  __shared__ float comb[256];
  __shared__ float cbuf[128];
  comb[f]       = pe[(size_t)g * 128 + f];
  comb[128 + f] = le[(size_t)g * 128 + f];
  __syncthreads();
  float acc = bfc[f];
  for (int k = 0; k < 256; ++k) acc += comb[k] * Wfc[(size_t)k * 128 + f];
  cbuf[f] = fmaxf(acc, 0.f);
  __syncthreads();
  if (f < 64) {
    const float* Wh[3] = {Wpkd, Wpki, Wba};
    const float* bh[3] = {bpkd, bpki, bba};
    #pragma unroll
    for (int hd = 0; hd < 3; ++hd) {
      float v = cbuf[f] * Wh[hd][f] + cbuf[f + 64] * Wh[hd][f + 64];
      #pragma unroll
      for (int d = 32; d; d >>= 1) v += __shfl_xor(v, d, 64);
      if (f == 0) out[(size_t)hd * G + g] = v + bh[hd][0];
    }
  }
}

// ============================================================================
static inline size_t alignUp(size_t x, size_t a) { return (x + a - 1) / a * a; }

extern "C" void kernel_launch(void* const* d_in, const int* in_sizes, int n_in,
                              void* d_out, int out_size, void* d_ws, size_t ws_size,
                              hipStream_t stream) {
  const float* px     = (const float*)d_in[0];
  const int*   pei    = (const int*)d_in[1];
  const int*   pbatch = (const int*)d_in[2];
  const float* lx     = (const float*)d_in[3];
  const int*   lei    = (const int*)d_in[4];
  const int*   lbatch = (const int*)d_in[5];
  const float* Wp1 = (const float*)d_in[7],  *bp1 = (const float*)d_in[8];
  const float* Wp2 = (const float*)d_in[9],  *bp2 = (const float*)d_in[10];
  const float* Wl1 = (const float*)d_in[11], *bl1 = (const float*)d_in[12];
  const float* Wl2 = (const float*)d_in[13], *bl2 = (const float*)d_in[14];
  const float* Wfc = (const float*)d_in[15], *bfc = (const float*)d_in[16];
  const float* Wpkd = (const float*)d_in[17], *bpkd = (const float*)d_in[18];
  const float* Wpki = (const float*)d_in[19], *bpki = (const float*)d_in[20];
  const float* Wba  = (const float*)d_in[21], *bba  = (const float*)d_in[22];
  float* out = (float*)d_out;

  const int Np = in_sizes[0] / 23, Ep = in_sizes[1] / 2;
  const int Nl = in_sizes[3] / 4,  El = in_sizes[4] / 2;
  const int G  = out_size / 3;
  const int nb_p = (Np + SCAN_CHUNK - 1) / SCAN_CHUNK;
  const int nb_l = (Nl + SCAN_CHUNK - 1) / SCAN_CHUNK;

  // ---- workspace layout ----
  char* base = (char*)d_ws;
  size_t off = 0;
  auto alloc = [&](size_t bytes) -> void* {
    void* p = base + off;
    off = alignUp(off + bytes, 256);
    return p;
  };
  size_t zero_beg = off;
  int*   degcnt_p = (int*)alloc((size_t)Np * 4);
  int*   cursor_p = (int*)alloc((size_t)Np * 4);
  int*   degcnt_l = (int*)alloc((size_t)Nl * 4);
  int*   cursor_l = (int*)alloc((size_t)Nl * 4);
  size_t zero_end = off;
  int*   offs_p  = (int*)alloc((size_t)(Np + 1) * 4);
  int*   offs_l  = (int*)alloc((size_t)(Nl + 1) * 4);
  int*   bsum_p  = (int*)alloc((size_t)nb_p * 4);
  int*   boffs_p = (int*)alloc((size_t)(nb_p + 1) * 4);
  int*   bsum_l  = (int*)alloc((size_t)nb_l * 4);
  int*   boffs_l = (int*)alloc((size_t)(nb_l + 1) * 4);
  int*   start_p = (int*)alloc((size_t)(G + 1) * 4);
  int*   start_l = (int*)alloc((size_t)(G + 1) * 4);
  float* dinv_p  = (float*)alloc((size_t)Np * 4);
  float* dinv_l  = (float*)alloc((size_t)Nl * 4);
  int*   ssrc_p  = (int*)alloc((size_t)Ep * 4);
  int*   ssrc_l  = (int*)alloc((size_t)El * 4);
  float* pe_mean = (float*)alloc((size_t)G * 128 * 4);
  float* le_mean = (float*)alloc((size_t)G * 128 * 4);
  float*    agg1_p = (float*)alloc((size_t)Np * 23 * 4);
  ushort_t* h1_p   = (ushort_t*)alloc((size_t)Np * 128 * 2);  // bf16
  float*    agg2_p = (float*)alloc((size_t)Np * 128 * 4);
  float*    h2_p   = (float*)alloc((size_t)Np * 128 * 4);
  float*    agg1_l = (float*)alloc((size_t)Nl * 4 * 4);
  float*    h1_l   = (float*)alloc((size_t)Nl * 128 * 4);
  float*    agg2_l = (float*)alloc((size_t)Nl * 128 * 4);
  float*    h2_l   = (float*)alloc((size_t)Nl * 128 * 4);
  if (off > ws_size) return;

  hipMemsetAsync(base + zero_beg, 0, zero_end - zero_beg, stream);

  const int* psrc = pei;
  const int* pdst = pei + Ep;
  const int* lsrc = lei;
  const int* ldst = lei + El;

  // ---- CSR build + per-node prep (fused across graphs) ----
  count_deg2_kernel<<<(Ep + El + 255) / 256, 256, 0, stream>>>(pdst, Ep, degcnt_p,
                                                               ldst, El, degcnt_l);
  node_prep_kernel<<<(Np + Nl + 255) / 256, 256, 0, stream>>>(
      degcnt_p, dinv_p, pbatch, start_p, Np,
      degcnt_l, dinv_l, lbatch, start_l, Nl, G);
  blocksum2_kernel<<<nb_p + nb_l, 256, 0, stream>>>(degcnt_p, Np, nb_p, bsum_p,
                                                    degcnt_l, Nl, bsum_l);
  exscan2_kernel<<<2, 1024, 0, stream>>>(bsum_p, boffs_p, nb_p, bsum_l, boffs_l, nb_l);
  scan_apply2_kernel<<<nb_p + nb_l, 256, 0, stream>>>(degcnt_p, boffs_p, offs_p, Np, nb_p,
                                                      degcnt_l, boffs_l, offs_l, Nl, nb_l);
  scatter2_kernel<<<(Ep + El + 255) / 256, 256, 0, stream>>>(
      psrc, pdst, offs_p, cursor_p, ssrc_p, Ep,
      lsrc, ldst, offs_l, cursor_l, ssrc_l, El);

  // ---- GNN layer 1 (both graphs fused) ----
  const int ablkP = (Np + 3) / 4, ablkL = (Nl + 3) / 4;
  agg1_both_kernel<<<ablkP + ablkL, 256, 0, stream>>>(
      px, ssrc_p, offs_p, dinv_p, agg1_p, Np, ablkP,
      lx, ssrc_l, offs_l, dinv_l, agg1_l, Nl);
  const int tblkP = (Np + 15) / 16, tblkL = (Nl + 15) / 16;
  transform1_both_kernel<<<tblkP + tblkL, 128, 0, stream>>>(
      agg1_p, Wp1, bp1, h1_p, Np, tblkP,
      agg1_l, Wl1, bl1, h1_l, Nl);

  // ---- GNN layer 2 (both graphs fused) ----
  agg2_both_kernel<<<ablkP + ablkL, 256, 0, stream>>>(
      h1_p, ssrc_p, offs_p, dinv_p, agg2_p, Np, ablkP,
      h1_l, ssrc_l, offs_l, dinv_l, agg2_l, Nl);
  transform2_both_kernel<<<tblkP + tblkL, 128, 0, stream>>>(
      agg2_p, Wp2, bp2, h2_p, Np, tblkP,
      agg2_l, Wl2, bl2, h2_l, Nl);

  // ---- pool (both graphs) + FC/heads ----
  pool_both_kernel<<<2 * G, 512, 0, stream>>>(h2_p, start_p, pe_mean,
                                              h2_l, start_l, le_mean, G);
  fc_heads_kernel<<<G, 128, 0, stream>>>(pe_mean, le_mean, Wfc, bfc,
                                         Wpkd, bpkd, Wpki, bpki, Wba, bba, out, G);
}

// Round 5
// 516.693 us; speedup vs baseline: 2.5475x; 1.1967x over previous
//
#include <hip/hip_runtime.h>

// ============================================================================
// ProteinLigandGNN: 2x GCNConv (protein), 2x GCNConv (ligand), mean-pool,
// FC + 3 heads.
//
// GCNConv: out = D^-1/2 (A+I) D^-1/2 (X W) + b  ==  (D^-1/2 (A+I) D^-1/2 X) W + b
// Aggregate FIRST (narrow feature space when possible), then transform.
// R3: protein h1 bf16 (halves layer-2 gather bytes); fused P+L launches.
// R4: layer-2 transform via MFMA bf16 (was 133us f32 VALU kernel, 20% occ,
//     6.5M LDS bank conflicts). agg2 outputs bf16; W2 pre-transposed to bf16.
//     D[f][node] = Wt x agg2^T so A- and B-frags are contiguous 16B loads.
// ============================================================================

typedef unsigned short ushort_t;
typedef short bf16x8 __attribute__((ext_vector_type(8)));
typedef float f32x4 __attribute__((ext_vector_type(4)));

#define SCAN_CHUNK 2048

static __device__ inline ushort_t f2bf(float f) {  // RNE f32->bf16
  unsigned u = __float_as_uint(f);
  unsigned r = (u + 0x7FFFu + ((u >> 16) & 1u)) >> 16;
  return (ushort_t)r;
}
static __device__ inline float bf2f(ushort_t b) {
  return __uint_as_float((unsigned)b << 16);
}

// ---------------- fused degree count (both graphs) ----------------
__global__ void count_deg2_kernel(const int* __restrict__ dstP, int Ep, int* __restrict__ degP,
                                  const int* __restrict__ dstL, int El, int* __restrict__ degL) {
  int e = blockIdx.x * blockDim.x + threadIdx.x;
  if (e < Ep) atomicAdd(&degP[dstP[e]], 1);
  else if (e < Ep + El) atomicAdd(&degL[dstL[e - Ep]], 1);
}

// ---------------- fused per-node prep: dinv + segment starts ----------------
__device__ inline void node_prep_dev(const int* deg, float* dinv, const int* batch,
                                     int* start, int i, int n, int G) {
  dinv[i] = rsqrtf((float)(deg[i] + 1));
  int b = batch[i];
  if (i == 0) { for (int g = 0; g <= b; ++g) start[g] = 0; }
  else { int pb = batch[i - 1]; for (int g = pb + 1; g <= b; ++g) start[g] = i; }
  if (i == n - 1) { for (int g = b + 1; g <= G; ++g) start[g] = n; }
}

__global__ void node_prep_kernel(const int* __restrict__ degP, float* __restrict__ dinvP,
                                 const int* __restrict__ batchP, int* __restrict__ startP, int nP,
                                 const int* __restrict__ degL, float* __restrict__ dinvL,
                                 const int* __restrict__ batchL, int* __restrict__ startL, int nL,
                                 int G) {
  int i = blockIdx.x * blockDim.x + threadIdx.x;
  if (i < nP) node_prep_dev(degP, dinvP, batchP, startP, i, nP, G);
  int j = i - nP;
  if (j >= 0 && j < nL) node_prep_dev(degL, dinvL, batchL, startL, j, nL, G);
}

// ---------------- W2 -> W2^T bf16 prep (both layers' weights) ----------------
__global__ void wprep_kernel(const float* __restrict__ Wp2, ushort_t* __restrict__ WtP,
                             const float* __restrict__ Wl2, ushort_t* __restrict__ WtL) {
  int i = blockIdx.x * blockDim.x + threadIdx.x;
  if (i < 16384) {
    int f = i >> 7, k = i & 127;
    WtP[i] = f2bf(Wp2[k * 128 + f]);
  } else if (i < 32768) {
    int j = i - 16384;
    int f = j >> 7, k = j & 127;
    WtL[j] = f2bf(Wl2[k * 128 + f]);
  }
}

// ---------------- hierarchical scan ----------------
__device__ inline void blocksum_dev(const int* cnt, int* bsum, int n, int b) {
  int t = threadIdx.x;
  int base = b * SCAN_CHUNK;
  int s = 0;
  for (int i = t; i < SCAN_CHUNK; i += 256) {
    int idx = base + i;
    if (idx < n) s += cnt[idx];
  }
  #pragma unroll
  for (int d = 32; d; d >>= 1) s += __shfl_down(s, d, 64);
  __shared__ int wt[4];
  int lane = t & 63, wid = t >> 6;
  if (lane == 0) wt[wid] = s;
  __syncthreads();
  if (t == 0) bsum[b] = wt[0] + wt[1] + wt[2] + wt[3];
}

__global__ __launch_bounds__(256) void blocksum2_kernel(
    const int* __restrict__ cntP, int nP, int nbP, int* __restrict__ bsumP,
    const int* __restrict__ cntL, int nL, int* __restrict__ bsumL) {
  int b = blockIdx.x;
  if (b < nbP) blocksum_dev(cntP, bsumP, nP, b);
  else blocksum_dev(cntL, bsumL, nL, b - nbP);
}

__device__ inline void exscan_small_dev(const int* bsum, int* boffs, int nb) {
  int t = threadIdx.x;
  int v = (t < nb) ? bsum[t] : 0;
  int lane = t & 63, wid = t >> 6;
  int inc = v;
  #pragma unroll
  for (int d = 1; d < 64; d <<= 1) {
    int u = __shfl_up(inc, d, 64);
    if (lane >= d) inc += u;
  }
  __shared__ int wt[16];
  if (lane == 63) wt[wid] = inc;
  __syncthreads();
  if (t < 16) {
    int w = wt[t];
    #pragma unroll
    for (int d = 1; d < 16; d <<= 1) {
      int u = __shfl_up(w, d, 64);
      if (t >= d) w += u;
    }
    wt[t] = w;
  }
  __syncthreads();
  int excl = (wid ? wt[wid - 1] : 0) + inc - v;
  if (t < nb) boffs[t] = excl;
  if (t == 0) boffs[nb] = wt[15];
}

__global__ __launch_bounds__(1024) void exscan2_kernel(const int* __restrict__ bsumP,
                                                       int* __restrict__ boffsP, int nbP,
                                                       const int* __restrict__ bsumL,
                                                       int* __restrict__ boffsL, int nbL) {
  if (blockIdx.x == 0) exscan_small_dev(bsumP, boffsP, nbP);
  else exscan_small_dev(bsumL, boffsL, nbL);
}

__device__ inline void scan_apply_dev(const int* cnt, const int* boffs, int* offs,
                                      int n, int nb, int b) {
  int t = threadIdx.x;
  int base = b * SCAN_CHUNK + t * 8;
  int v[8];
  int s = 0;
  #pragma unroll
  for (int j = 0; j < 8; ++j) {
    int idx = base + j;
    v[j] = (idx < n) ? cnt[idx] : 0;
    s += v[j];
  }
  int lane = t & 63, wid = t >> 6;
  int inc = s;
  #pragma unroll
  for (int d = 1; d < 64; d <<= 1) {
    int u = __shfl_up(inc, d, 64);
    if (lane >= d) inc += u;
  }
  __shared__ int wt[4];
  if (lane == 63) wt[wid] = inc;
  __syncthreads();
  int wadd = 0;
  for (int w = 0; w < wid; ++w) wadd += wt[w];
  int excl = boffs[b] + wadd + inc - s;
  #pragma unroll
  for (int j = 0; j < 8; ++j) {
    int idx = base + j;
    if (idx < n) offs[idx] = excl;
    excl += v[j];
  }
  if (b == 0 && t == 0) offs[n] = boffs[nb];
}

__global__ __launch_bounds__(256) void scan_apply2_kernel(
    const int* __restrict__ cntP, const int* __restrict__ boffsP, int* __restrict__ offsP,
    int nP, int nbP,
    const int* __restrict__ cntL, const int* __restrict__ boffsL, int* __restrict__ offsL,
    int nL, int nbL) {
  int b = blockIdx.x;
  if (b < nbP) scan_apply_dev(cntP, boffsP, offsP, nP, nbP, b);
  else scan_apply_dev(cntL, boffsL, offsL, nL, nbL, b - nbP);
}

// ---------------- fused scatter ----------------
__global__ void scatter2_kernel(const int* __restrict__ srcP, const int* __restrict__ dstP,
                                const int* __restrict__ offsP, int* __restrict__ curP,
                                int* __restrict__ ssrcP, int Ep,
                                const int* __restrict__ srcL, const int* __restrict__ dstL,
                                const int* __restrict__ offsL, int* __restrict__ curL,
                                int* __restrict__ ssrcL, int El) {
  int e = blockIdx.x * blockDim.x + threadIdx.x;
  if (e < Ep) {
    int d = dstP[e];
    ssrcP[offsP[d] + atomicAdd(&curP[d], 1)] = srcP[e];
  } else if (e < Ep + El) {
    int e2 = e - Ep;
    int d = dstL[e2];
    ssrcL[offsL[d] + atomicAdd(&curL[d], 1)] = srcL[e2];
  }
}

// ---------------- layer-1 aggregation: lane-grouped (LPG lanes per edge) ----
template<int F, int LPG>
__device__ inline void agg_small_dev(const float* __restrict__ x, const int* __restrict__ ssrc,
                                     const int* __restrict__ offs, const float* __restrict__ dinv,
                                     float* __restrict__ out, int node, int n) {
  if (node >= n) return;
  constexpr int G = 64 / LPG;  // edges in flight per wave
  int lane = threadIdx.x & 63;
  int grp = lane / LPG, l = lane % LPG;
  int beg = offs[node], end = offs[node + 1];
  float acc = 0.f;
  for (int b0 = beg; b0 < end; b0 += 64) {
    int m = end - b0; if (m > 64) m = 64;
    int sl = 0; float wl = 0.f;
    if (lane < m) { sl = ssrc[b0 + lane]; wl = dinv[sl]; }
    for (int k = 0; k < m; k += G) {
      int idx = k + grp;
      int s = __shfl(sl, idx, 64);
      float w = __shfl(wl, idx, 64);
      if (l < F) acc += x[(size_t)s * F + l] * w;
    }
  }
  #pragma unroll
  for (int d = LPG; d < 64; d <<= 1) acc += __shfl_xor(acc, d, 64);
  if (grp == 0 && l < F) {
    float di = dinv[node];
    acc = (acc + x[(size_t)node * F + l] * di) * di;
    out[(size_t)node * F + l] = acc;
  }
}

__global__ void agg1_both_kernel(const float* __restrict__ xP, const int* __restrict__ ssrcP,
                                 const int* __restrict__ offsP, const float* __restrict__ dinvP,
                                 float* __restrict__ outP, int nP, int nblkP,
                                 const float* __restrict__ xL, const int* __restrict__ ssrcL,
                                 const int* __restrict__ offsL, const float* __restrict__ dinvL,
                                 float* __restrict__ outL, int nL) {
  int wave_in_blk = threadIdx.x >> 6;
  if ((int)blockIdx.x < nblkP) {
    int node = blockIdx.x * 4 + wave_in_blk;
    agg_small_dev<23, 32>(xP, ssrcP, offsP, dinvP, outP, node, nP);
  } else {
    int node = (blockIdx.x - nblkP) * 4 + wave_in_blk;
    agg_small_dev<4, 4>(xL, ssrcL, offsL, dinvL, outL, node, nL);
  }
}

// ---------------- layer-2 aggregation (128 features) -> bf16 out ----------------
__device__ inline void agg128_bf_dev(const ushort_t* __restrict__ x, const int* __restrict__ ssrc,
                                     const int* __restrict__ offs, const float* __restrict__ dinv,
                                     ushort_t* __restrict__ out, int node, int n) {
  if (node >= n) return;
  int lane = threadIdx.x & 63;
  int beg = offs[node], end = offs[node + 1];
  float ax = 0.f, ay = 0.f;
  const ushort2* x2 = (const ushort2*)x;  // row = 64 ushort2 (256B)
  for (int b0 = beg; b0 < end; b0 += 64) {
    int m = end - b0; if (m > 64) m = 64;
    int sl = 0; float wl = 0.f;
    if (lane < m) { sl = ssrc[b0 + lane]; wl = dinv[sl]; }
    for (int k = 0; k < m; ++k) {
      int s = __shfl(sl, k, 64);
      float w = __shfl(wl, k, 64);
      ushort2 v = x2[(size_t)s * 64 + lane];
      ax += bf2f(v.x) * w;
      ay += bf2f(v.y) * w;
    }
  }
  float di = dinv[node];
  ushort2 vi = x2[(size_t)node * 64 + lane];
  ax = (ax + bf2f(vi.x) * di) * di;
  ay = (ay + bf2f(vi.y) * di) * di;
  ushort2 o; o.x = f2bf(ax); o.y = f2bf(ay);
  ((ushort2*)out)[(size_t)node * 64 + lane] = o;
}

__device__ inline void agg128_f32_dev(const float* __restrict__ x, const int* __restrict__ ssrc,
                                      const int* __restrict__ offs, const float* __restrict__ dinv,
                                      ushort_t* __restrict__ out, int node, int n) {
  if (node >= n) return;
  int lane = threadIdx.x & 63;
  int beg = offs[node], end = offs[node + 1];
  float2 acc; acc.x = 0.f; acc.y = 0.f;
  const float2* x2 = (const float2*)x;
  for (int b0 = beg; b0 < end; b0 += 64) {
    int m = end - b0; if (m > 64) m = 64;
    int sl = 0; float wl = 0.f;
    if (lane < m) { sl = ssrc[b0 + lane]; wl = dinv[sl]; }
    for (int k = 0; k < m; ++k) {
      int s = __shfl(sl, k, 64);
      float w = __shfl(wl, k, 64);
      float2 v = x2[(size_t)s * 64 + lane];
      acc.x += v.x * w; acc.y += v.y * w;
    }
  }
  float di = dinv[node];
  float2 vi = x2[(size_t)node * 64 + lane];
  acc.x = (acc.x + vi.x * di) * di;
  acc.y = (acc.y + vi.y * di) * di;
  ushort2 o; o.x = f2bf(acc.x); o.y = f2bf(acc.y);
  ((ushort2*)out)[(size_t)node * 64 + lane] = o;
}

__global__ void agg2_both_kernel(const ushort_t* __restrict__ xP, const int* __restrict__ ssrcP,
                                 const int* __restrict__ offsP, const float* __restrict__ dinvP,
                                 ushort_t* __restrict__ outP, int nP, int nblkP,
                                 const float* __restrict__ xL, const int* __restrict__ ssrcL,
                                 const int* __restrict__ offsL, const float* __restrict__ dinvL,
                                 ushort_t* __restrict__ outL, int nL) {
  int wave_in_blk = threadIdx.x >> 6;
  if ((int)blockIdx.x < nblkP) {
    int node = blockIdx.x * 4 + wave_in_blk;
    agg128_bf_dev(xP, ssrcP, offsP, dinvP, outP, node, nP);
  } else {
    int node = (blockIdx.x - nblkP) * 4 + wave_in_blk;
    agg128_f32_dev(xL, ssrcL, offsL, dinvL, outL, node, nL);
  }
}

// ---------------- layer-1 transform (f32 VALU; K=23/4 not MFMA-shaped) -------
__device__ inline void store_out(float* p, float v) { *p = v; }
__device__ inline void store_out(ushort_t* p, float v) { *p = f2bf(v); }

template<int KIN, int NPB, typename OutT>
__device__ inline void transform_dev(float* smem, const float* __restrict__ in,
                                     const float* __restrict__ W, const float* __restrict__ bias,
                                     OutT* __restrict__ out, int n, int blk) {
  constexpr int KT = (KIN > 64) ? 64 : KIN;
  float* Ws = smem;                 // KT*128
  float* rowsT = smem + KT * 128;   // KIN*NPB, [k][j]
  const int f = threadIdx.x;
  const int base = blk * NPB;

  for (int i = f; i < NPB * KIN; i += 128) {
    int j = i / KIN, k = i - j * KIN;
    int node = base + j;
    rowsT[k * NPB + j] = (node < n) ? in[(size_t)node * KIN + k] : 0.f;
  }

  float acc[NPB];
  #pragma unroll
  for (int j = 0; j < NPB; ++j) acc[j] = 0.f;

  for (int k0 = 0; k0 < KIN; k0 += KT) {
    __syncthreads();
    int kt = KIN - k0; if (kt > KT) kt = KT;
    for (int i = f; i < kt * 128; i += 128) Ws[i] = W[(size_t)k0 * 128 + i];
    __syncthreads();
    for (int k = 0; k < kt; ++k) {
      float w = Ws[k * 128 + f];
      const float4* rt = (const float4*)&rowsT[(k0 + k) * NPB];
      #pragma unroll
      for (int j4 = 0; j4 < NPB / 4; ++j4) {
        float4 r = rt[j4];
        acc[j4 * 4 + 0] += r.x * w;
        acc[j4 * 4 + 1] += r.y * w;
        acc[j4 * 4 + 2] += r.z * w;
        acc[j4 * 4 + 3] += r.w * w;
      }
    }
  }
  float bv = bias[f];
  #pragma unroll
  for (int j = 0; j < NPB; ++j) {
    int node = base + j;
    if (node < n) {
      float v = acc[j] + bv;
      store_out(&out[(size_t)node * 128 + f], v > 0.f ? v : 0.f);
    }
  }
}

// layer-1 transforms: protein KIN=23 -> bf16 out, ligand KIN=4 -> f32 out
__global__ __launch_bounds__(128) void transform1_both_kernel(
    const float* __restrict__ inP, const float* __restrict__ WP, const float* __restrict__ bP,
    ushort_t* __restrict__ outP, int nP, int nblkP,
    const float* __restrict__ inL, const float* __restrict__ WL, const float* __restrict__ bL,
    float* __restrict__ outL, int nL) {
  __shared__ float smem[23 * 128 + 23 * 16];
  if ((int)blockIdx.x < nblkP)
    transform_dev<23, 16, ushort_t>(smem, inP, WP, bP, outP, nP, blockIdx.x);
  else
    transform_dev<4, 16, float>(smem, inL, WL, bL, outL, nL, blockIdx.x - nblkP);
}

// ---------------- layer-2 transform via MFMA bf16 ----------------
// Computes h2[node][f] = relu( (agg2 @ W)[node][f] + b[f] ) as D[f][node] =
// Wt(16f x 128k) x agg2^T(128k x 128node) per block tile.
// Block: 512 thr (8 waves), 128 nodes; wave w owns f-strip [16w, 16w+16).
// agg2 node rows staged to LDS in fragment-major order (lane-linear b128 reads).
__global__ __launch_bounds__(512) void t2_mfma_kernel(
    const ushort_t* __restrict__ aggP, const ushort_t* __restrict__ WtP,
    const float* __restrict__ bP, float* __restrict__ h2P, int nP, int nblkP,
    const ushort_t* __restrict__ aggL, const ushort_t* __restrict__ WtL,
    const float* __restrict__ bL, float* __restrict__ h2L, int nL) {
  const ushort_t* agg; const ushort_t* Wt; const float* bias; float* out; int n, n0;
  if ((int)blockIdx.x < nblkP) {
    agg = aggP; Wt = WtP; bias = bP; out = h2P; n = nP; n0 = blockIdx.x * 128;
  } else {
    agg = aggL; Wt = WtL; bias = bL; out = h2L; n = nL;
    n0 = (blockIdx.x - nblkP) * 128;
  }
  __shared__ __align__(16) short sB[16384];  // 32KB: 128 nodes x 128 k bf16
  const int t = threadIdx.x;
  const int lane = t & 63;
  const int ws = t >> 6;

  // ---- stage agg2 rows -> LDS, fragment-major: 16B chunk (g,kc,b,m) at
  //      ((g*4+kc)*64 + b*16 + m) * 16B, where node = g*16+m, k-chunk c = kc*4+b
  #pragma unroll
  for (int c4 = 0; c4 < 4; ++c4) {
    int cidx = t + c4 * 512;       // 0..2047
    int node = cidx >> 4, c = cidx & 15;
    uint4 v = make_uint4(0u, 0u, 0u, 0u);
    if (n0 + node < n) v = *(const uint4*)&agg[(size_t)(n0 + node) * 128 + c * 8];
    int off16 = (((node >> 4) * 4 + (c >> 2)) * 64) + (c & 3) * 16 + (node & 15);
    *(uint4*)&sB[off16 * 8] = v;
  }

  // ---- A-frags: Wt rows (f = fs + lane%16), k = kc*32 + (lane/16)*8 .. +7
  const int fs = ws * 16;
  bf16x8 a[4];
  #pragma unroll
  for (int kc = 0; kc < 4; ++kc)
    a[kc] = *(const bf16x8*)&Wt[(size_t)(fs + (lane & 15)) * 128 + kc * 32 + (lane >> 4) * 8];

  __syncthreads();

  f32x4 acc[8];
  #pragma unroll
  for (int g = 0; g < 8; ++g) acc[g] = (f32x4){0.f, 0.f, 0.f, 0.f};

  #pragma unroll
  for (int g = 0; g < 8; ++g) {
    #pragma unroll
    for (int kc = 0; kc < 4; ++kc) {
      bf16x8 b = *(const bf16x8*)&sB[(((g * 4 + kc) * 64) + lane) * 8];
      acc[g] = __builtin_amdgcn_mfma_f32_16x16x32_bf16(a[kc], b, acc[g], 0, 0, 0);
    }
  }

  // ---- epilogue: D row = f-local = (lane>>4)*4 + reg; col = node-local = lane&15
  const int f0 = fs + ((lane >> 4) << 2);
  float4 bv = *(const float4*)&bias[f0];
  #pragma unroll
  for (int g = 0; g < 8; ++g) {
    int node = n0 + g * 16 + (lane & 15);
    if (node < n) {
      float4 o;
      o.x = fmaxf(acc[g][0] + bv.x, 0.f);
      o.y = fmaxf(acc[g][1] + bv.y, 0.f);
      o.z = fmaxf(acc[g][2] + bv.z, 0.f);
      o.w = fmaxf(acc[g][3] + bv.w, 0.f);
      *(float4*)&out[(size_t)node * 128 + f0] = o;
    }
  }
}

// ---------------- segmented mean-pool (both graphs) ----------------
__device__ inline void pool_dev(const float* __restrict__ h, const int* __restrict__ start,
                                float* __restrict__ mean, int g) {
  int t = threadIdx.x;
  int f = t & 127, r = t >> 7;
  int beg = start[g], end = start[g + 1];
  float acc = 0.f;
  for (int i = beg + r; i < end; i += 4)
    acc += h[(size_t)i * 128 + f];
  __shared__ float red[4][128];
  red[r][f] = acc;
  __syncthreads();
  if (r == 0) {
    float s = red[0][f] + red[1][f] + red[2][f] + red[3][f];
    float c = (float)(end - beg);
    mean[(size_t)g * 128 + f] = s / fmaxf(c, 1.f);
  }
}

__global__ __launch_bounds__(512) void pool_both_kernel(
    const float* __restrict__ hP, const int* __restrict__ startP, float* __restrict__ meanP,
    const float* __restrict__ hL, const int* __restrict__ startL, float* __restrict__ meanL,
    int G) {
  int g = blockIdx.x;
  if (g < G) pool_dev(hP, startP, meanP, g);
  else pool_dev(hL, startL, meanL, g - G);
}

// ---------------- final FC + 3 heads ----------------
__global__ __launch_bounds__(128) void fc_heads_kernel(
    const float* __restrict__ pe, const float* __restrict__ le,
    const float* __restrict__ Wfc, const float* __restrict__ bfc,
    const float* __restrict__ Wpkd, const float* __restrict__ bpkd,
    const float* __restrict__ Wpki, const float* __restrict__ bpki,
    const float* __restrict__ Wba, const float* __restrict__ bba,
    float* __restrict__ out, int G) {
  int g = blockIdx.x, f = threadIdx.x;
  __shared__ float comb[256];
  __shared__ float cbuf[128];
  comb[f]       = pe[(size_t)g * 128 + f];
  comb[128 + f] = le[(size_t)g * 128 + f];
  __syncthreads();
  float acc = bfc[f];
  for (int k = 0; k < 256; ++k) acc += comb[k] * Wfc[(size_t)k * 128 + f];
  cbuf[f] = fmaxf(acc, 0.f);
  __syncthreads();
  if (f < 64) {
    const float* Wh[3] = {Wpkd, Wpki, Wba};
    const float* bh[3] = {bpkd, bpki, bba};
    #pragma unroll
    for (int hd = 0; hd < 3; ++hd) {
      float v = cbuf[f] * Wh[hd][f] + cbuf[f + 64] * Wh[hd][f + 64];
      #pragma unroll
      for (int d = 32; d; d >>= 1) v += __shfl_xor(v, d, 64);
      if (f == 0) out[(size_t)hd * G + g] = v + bh[hd][0];
    }
  }
}

// ============================================================================
static inline size_t alignUp(size_t x, size_t a) { return (x + a - 1) / a * a; }

extern "C" void kernel_launch(void* const* d_in, const int* in_sizes, int n_in,
                              void* d_out, int out_size, void* d_ws, size_t ws_size,
                              hipStream_t stream) {
  const float* px     = (const float*)d_in[0];
  const int*   pei    = (const int*)d_in[1];
  const int*   pbatch = (const int*)d_in[2];
  const float* lx     = (const float*)d_in[3];
  const int*   lei    = (const int*)d_in[4];
  const int*   lbatch = (const int*)d_in[5];
  const float* Wp1 = (const float*)d_in[7],  *bp1 = (const float*)d_in[8];
  const float* Wp2 = (const float*)d_in[9],  *bp2 = (const float*)d_in[10];
  const float* Wl1 = (const float*)d_in[11], *bl1 = (const float*)d_in[12];
  const float* Wl2 = (const float*)d_in[13], *bl2 = (const float*)d_in[14];
  const float* Wfc = (const float*)d_in[15], *bfc = (const float*)d_in[16];
  const float* Wpkd = (const float*)d_in[17], *bpkd = (const float*)d_in[18];
  const float* Wpki = (const float*)d_in[19], *bpki = (const float*)d_in[20];
  const float* Wba  = (const float*)d_in[21], *bba  = (const float*)d_in[22];
  float* out = (float*)d_out;

  const int Np = in_sizes[0] / 23, Ep = in_sizes[1] / 2;
  const int Nl = in_sizes[3] / 4,  El = in_sizes[4] / 2;
  const int G  = out_size / 3;
  const int nb_p = (Np + SCAN_CHUNK - 1) / SCAN_CHUNK;
  const int nb_l = (Nl + SCAN_CHUNK - 1) / SCAN_CHUNK;

  // ---- workspace layout ----
  char* base = (char*)d_ws;
  size_t off = 0;
  auto alloc = [&](size_t bytes) -> void* {
    void* p = base + off;
    off = alignUp(off + bytes, 256);
    return p;
  };
  size_t zero_beg = off;
  int*   degcnt_p = (int*)alloc((size_t)Np * 4);
  int*   cursor_p = (int*)alloc((size_t)Np * 4);
  int*   degcnt_l = (int*)alloc((size_t)Nl * 4);
  int*   cursor_l = (int*)alloc((size_t)Nl * 4);
  size_t zero_end = off;
  int*   offs_p  = (int*)alloc((size_t)(Np + 1) * 4);
  int*   offs_l  = (int*)alloc((size_t)(Nl + 1) * 4);
  int*   bsum_p  = (int*)alloc((size_t)nb_p * 4);
  int*   boffs_p = (int*)alloc((size_t)(nb_p + 1) * 4);
  int*   bsum_l  = (int*)alloc((size_t)nb_l * 4);
  int*   boffs_l = (int*)alloc((size_t)(nb_l + 1) * 4);
  int*   start_p = (int*)alloc((size_t)(G + 1) * 4);
  int*   start_l = (int*)alloc((size_t)(G + 1) * 4);
  float* dinv_p  = (float*)alloc((size_t)Np * 4);
  float* dinv_l  = (float*)alloc((size_t)Nl * 4);
  int*   ssrc_p  = (int*)alloc((size_t)Ep * 4);
  int*   ssrc_l  = (int*)alloc((size_t)El * 4);
  float* pe_mean = (float*)alloc((size_t)G * 128 * 4);
  float* le_mean = (float*)alloc((size_t)G * 128 * 4);
  ushort_t* wt2_p = (ushort_t*)alloc((size_t)16384 * 2);
  ushort_t* wt2_l = (ushort_t*)alloc((size_t)16384 * 2);
  float*    agg1_p = (float*)alloc((size_t)Np * 23 * 4);
  ushort_t* h1_p   = (ushort_t*)alloc((size_t)Np * 128 * 2);  // bf16
  ushort_t* agg2_p = (ushort_t*)alloc((size_t)Np * 128 * 2);  // bf16
  float*    h2_p   = (float*)alloc((size_t)Np * 128 * 4);
  float*    agg1_l = (float*)alloc((size_t)Nl * 4 * 4);
  float*    h1_l   = (float*)alloc((size_t)Nl * 128 * 4);
  ushort_t* agg2_l = (ushort_t*)alloc((size_t)Nl * 128 * 2);  // bf16
  float*    h2_l   = (float*)alloc((size_t)Nl * 128 * 4);
  if (off > ws_size) return;

  hipMemsetAsync(base + zero_beg, 0, zero_end - zero_beg, stream);

  const int* psrc = pei;
  const int* pdst = pei + Ep;
  const int* lsrc = lei;
  const int* ldst = lei + El;

  // ---- weight prep (independent of everything else) ----
  wprep_kernel<<<128, 256, 0, stream>>>(Wp2, wt2_p, Wl2, wt2_l);

  // ---- CSR build + per-node prep (fused across graphs) ----
  count_deg2_kernel<<<(Ep + El + 255) / 256, 256, 0, stream>>>(pdst, Ep, degcnt_p,
                                                               ldst, El, degcnt_l);
  node_prep_kernel<<<(Np + Nl + 255) / 256, 256, 0, stream>>>(
      degcnt_p, dinv_p, pbatch, start_p, Np,
      degcnt_l, dinv_l, lbatch, start_l, Nl, G);
  blocksum2_kernel<<<nb_p + nb_l, 256, 0, stream>>>(degcnt_p, Np, nb_p, bsum_p,
                                                    degcnt_l, Nl, bsum_l);
  exscan2_kernel<<<2, 1024, 0, stream>>>(bsum_p, boffs_p, nb_p, bsum_l, boffs_l, nb_l);
  scan_apply2_kernel<<<nb_p + nb_l, 256, 0, stream>>>(degcnt_p, boffs_p, offs_p, Np, nb_p,
                                                      degcnt_l, boffs_l, offs_l, Nl, nb_l);
  scatter2_kernel<<<(Ep + El + 255) / 256, 256, 0, stream>>>(
      psrc, pdst, offs_p, cursor_p, ssrc_p, Ep,
      lsrc, ldst, offs_l, cursor_l, ssrc_l, El);

  // ---- GNN layer 1 (both graphs fused) ----
  const int ablkP = (Np + 3) / 4, ablkL = (Nl + 3) / 4;
  agg1_both_kernel<<<ablkP + ablkL, 256, 0, stream>>>(
      px, ssrc_p, offs_p, dinv_p, agg1_p, Np, ablkP,
      lx, ssrc_l, offs_l, dinv_l, agg1_l, Nl);
  const int tblkP = (Np + 15) / 16, tblkL = (Nl + 15) / 16;
  transform1_both_kernel<<<tblkP + tblkL, 128, 0, stream>>>(
      agg1_p, Wp1, bp1, h1_p, Np, tblkP,
      agg1_l, Wl1, bl1, h1_l, Nl);

  // ---- GNN layer 2 (both graphs fused) ----
  agg2_both_kernel<<<ablkP + ablkL, 256, 0, stream>>>(
      h1_p, ssrc_p, offs_p, dinv_p, agg2_p, Np, ablkP,
      h1_l, ssrc_l, offs_l, dinv_l, agg2_l, Nl);
  const int mblkP = (Np + 127) / 128, mblkL = (Nl + 127) / 128;
  t2_mfma_kernel<<<mblkP + mblkL, 512, 0, stream>>>(
      agg2_p, wt2_p, bp2, h2_p, Np, mblkP,
      agg2_l, wt2_l, bl2, h2_l, Nl);

  // ---- pool (both graphs) + FC/heads ----
  pool_both_kernel<<<2 * G, 512, 0, stream>>>(h2_p, start_p, pe_mean,
                                              h2_l, start_l, le_mean, G);
  fc_heads_kernel<<<G, 128, 0, stream>>>(pe_mean, le_mean, Wfc, bfc,
                                         Wpkd, bpkd, Wpki, bpki, Wba, bba, out, G);
}